// Round 1
// baseline (3191.029 us; speedup 1.0000x reference)
//
#include <hip/hip_runtime.h>
#include <cstdint>
#include <cstddef>

// Problem constants
#define EE        800000
#define NC        100000
#define NM        50000
#define ND        10000
#define NSLOTS    320000   // sum of dst sizes over 6 relations

// relation order: 0=c->m, 1=m->d, 2=c->d, 3=m->c, 4=d->m, 5=d->c
// slot bases in concatenated deg/off array:
// rel0 (dst m, 50k): 0; rel1 (dst d, 10k): 50000; rel2 (dst d, 10k): 60000;
// rel3 (dst c,100k): 70000; rel4 (dst m, 50k): 170000; rel5 (dst c,100k): 220000

__global__ __launch_bounds__(256) void zero_k(int* p, int n) {
    int i = blockIdx.x * 256 + threadIdx.x;
    if (i < n) p[i] = 0;
}

__global__ __launch_bounds__(256) void hist_k(const int* __restrict__ dst, int* __restrict__ deg, int n) {
    int i = blockIdx.x * 256 + threadIdx.x;
    if (i < n) atomicAdd(&deg[dst[i]], 1);
}

// exclusive scan, 2048 elements per block, in-place; block totals -> bsum
__global__ __launch_bounds__(256) void scan_part_k(int* data, int n, int* bsum) {
    __shared__ int lds[256];
    int tid = threadIdx.x;
    int base = blockIdx.x * 2048 + tid * 8;
    int v[8];
    int tot = 0;
#pragma unroll
    for (int t = 0; t < 8; ++t) {
        int idx = base + t;
        int x = (idx < n) ? data[idx] : 0;
        v[t] = tot;
        tot += x;
    }
    lds[tid] = tot;
    __syncthreads();
    for (int o = 1; o < 256; o <<= 1) {
        int x = 0;
        if (tid >= o) x = lds[tid - o];
        __syncthreads();
        lds[tid] += x;
        __syncthreads();
    }
    int texcl = lds[tid] - tot;
    if (tid == 255) bsum[blockIdx.x] = lds[255];
#pragma unroll
    for (int t = 0; t < 8; ++t) {
        int idx = base + t;
        if (idx < n) data[idx] = texcl + v[t];
    }
}

__global__ __launch_bounds__(256) void scan_bsum_k(int* bsum, int nb, int* data, int n) {
    __shared__ int lds[256];
    int tid = threadIdx.x;
    int x = (tid < nb) ? bsum[tid] : 0;
    lds[tid] = x;
    __syncthreads();
    for (int o = 1; o < 256; o <<= 1) {
        int y = 0;
        if (tid >= o) y = lds[tid - o];
        __syncthreads();
        lds[tid] += y;
        __syncthreads();
    }
    if (tid < nb) bsum[tid] = lds[tid] - x;  // exclusive block base
    if (tid == 255) data[n] = lds[255];      // grand total (== 6*EE)
}

__global__ __launch_bounds__(256) void scan_add_k(int* data, int n, const int* __restrict__ bsum, int* __restrict__ cursor) {
    int base = blockIdx.x * 2048 + threadIdx.x * 8;
    int add = bsum[blockIdx.x];
#pragma unroll
    for (int t = 0; t < 8; ++t) {
        int idx = base + t;
        if (idx < n) {
            int val = data[idx] + add;
            data[idx] = val;
            cursor[idx] = val;
        }
    }
}

__global__ __launch_bounds__(256) void scatter_k(const int* __restrict__ src, const int* __restrict__ dst,
                                                 int* __restrict__ cursor, int* __restrict__ csr, int n) {
    int i = blockIdx.x * 256 + threadIdx.x;
    if (i < n) {
        int p = atomicAdd(&cursor[dst[i]], 1);
        csr[p] = src[i];
    }
}

// ---- Layer 1: h_t = relu(0.5*(mean1@Wl1 + mean2@Wl2 + x@(Wr1+Wr2) + b_a + b_b))
// block = 256 threads, tile = 32 dst nodes. F_in = 128, F_out = 64.
__global__ __launch_bounds__(256) void layer1_k(
    const float* __restrict__ xs1, const float* __restrict__ xs2,
    const float* __restrict__ xdst,
    const int* __restrict__ off1, const int* __restrict__ off2,
    const int* __restrict__ csr,
    const float* __restrict__ Wl1, const float* __restrict__ Wl2,
    const float* __restrict__ Wr1, const float* __restrict__ Wr2,
    const float* __restrict__ ba, const float* __restrict__ bb,
    float* __restrict__ hout, int n)
{
    __shared__ float s1[32][128];
    __shared__ float s2[32][128];
    __shared__ float xd[32][128];
    int tid = threadIdx.x;
    int node0 = blockIdx.x * 32;

    // cooperative x_dst tile load
    for (int idx = tid; idx < 32 * 128; idx += 256) {
        int nn = idx >> 7, f = idx & 127;
        int g = node0 + nn;
        xd[nn][f] = (g < n) ? xdst[(size_t)g * 128 + f] : 0.f;
    }

    int w = tid >> 6, l = tid & 63;  // wave id, lane
    for (int ni = 0; ni < 8; ++ni) {
        int nn = w * 8 + ni;
        int g = node0 + nn;
        if (g < n) {
            {
                int e0 = off1[g], e1 = off1[g + 1];
                float a0 = 0.f, a1 = 0.f;
                int e = e0;
                for (; e + 1 < e1; e += 2) {
                    int nA = csr[e], nB = csr[e + 1];
                    float2 vA = *((const float2*)xs1 + (size_t)nA * 64 + l);
                    float2 vB = *((const float2*)xs1 + (size_t)nB * 64 + l);
                    a0 += vA.x + vB.x;
                    a1 += vA.y + vB.y;
                }
                if (e < e1) {
                    float2 vA = *((const float2*)xs1 + (size_t)csr[e] * 64 + l);
                    a0 += vA.x; a1 += vA.y;
                }
                float sc = 1.f / fmaxf((float)(e1 - e0), 1.f);
                s1[nn][2 * l] = a0 * sc;
                s1[nn][2 * l + 1] = a1 * sc;
            }
            {
                int e0 = off2[g], e1 = off2[g + 1];
                float a0 = 0.f, a1 = 0.f;
                int e = e0;
                for (; e + 1 < e1; e += 2) {
                    int nA = csr[e], nB = csr[e + 1];
                    float2 vA = *((const float2*)xs2 + (size_t)nA * 64 + l);
                    float2 vB = *((const float2*)xs2 + (size_t)nB * 64 + l);
                    a0 += vA.x + vB.x;
                    a1 += vA.y + vB.y;
                }
                if (e < e1) {
                    float2 vA = *((const float2*)xs2 + (size_t)csr[e] * 64 + l);
                    a0 += vA.x; a1 += vA.y;
                }
                float sc = 1.f / fmaxf((float)(e1 - e0), 1.f);
                s2[nn][2 * l] = a0 * sc;
                s2[nn][2 * l + 1] = a1 * sc;
            }
        }
    }
    __syncthreads();

    int j = tid & 63, ng = tid >> 6;
    float acc[8];
    float bj = ba[j] + bb[j];
#pragma unroll
    for (int ni = 0; ni < 8; ++ni) acc[ni] = bj;
#pragma unroll 4
    for (int k = 0; k < 128; ++k) {
        float w1 = Wl1[k * 64 + j];
        float w2 = Wl2[k * 64 + j];
        float wr = Wr1[k * 64 + j] + Wr2[k * 64 + j];
#pragma unroll
        for (int ni = 0; ni < 8; ++ni) {
            int nn = ng * 8 + ni;
            acc[ni] += s1[nn][k] * w1 + s2[nn][k] * w2 + xd[nn][k] * wr;
        }
    }
#pragma unroll
    for (int ni = 0; ni < 8; ++ni) {
        int nn = ng * 8 + ni;
        int g = node0 + nn;
        if (g < n) hout[(size_t)g * 64 + j] = fmaxf(0.5f * acc[ni], 0.f);
    }
}

// ---- Layer 2 + residual: out = 0.5*(m1@Wl1 + m2@Wl2 + h@(Wr1+Wr2) + ba + bb) + x@Wres + bres
__global__ __launch_bounds__(256) void layer2_k(
    const float* __restrict__ hs1, const float* __restrict__ hs2,
    const float* __restrict__ hdst, const float* __restrict__ xres,
    const int* __restrict__ off1, const int* __restrict__ off2,
    const int* __restrict__ csr,
    const float* __restrict__ Wl1, const float* __restrict__ Wl2,
    const float* __restrict__ Wr1, const float* __restrict__ Wr2,
    const float* __restrict__ ba, const float* __restrict__ bb,
    const float* __restrict__ Wres, const float* __restrict__ bres,
    float* __restrict__ out, int n)
{
    __shared__ float s1[32][64];
    __shared__ float s2[32][64];
    __shared__ float hd[32][64];
    __shared__ float xd[32][128];
    int tid = threadIdx.x;
    int node0 = blockIdx.x * 32;

    for (int idx = tid; idx < 32 * 64; idx += 256) {
        int nn = idx >> 6, f = idx & 63;
        int g = node0 + nn;
        hd[nn][f] = (g < n) ? hdst[(size_t)g * 64 + f] : 0.f;
    }
    for (int idx = tid; idx < 32 * 128; idx += 256) {
        int nn = idx >> 7, f = idx & 127;
        int g = node0 + nn;
        xd[nn][f] = (g < n) ? xres[(size_t)g * 128 + f] : 0.f;
    }

    int w = tid >> 6, l = tid & 63;
    for (int ni = 0; ni < 8; ++ni) {
        int nn = w * 8 + ni;
        int g = node0 + nn;
        if (g < n) {
            {
                int e0 = off1[g], e1 = off1[g + 1];
                float a = 0.f;
                int e = e0;
                for (; e + 1 < e1; e += 2) {
                    int nA = csr[e], nB = csr[e + 1];
                    a += hs1[(size_t)nA * 64 + l] + hs1[(size_t)nB * 64 + l];
                }
                if (e < e1) a += hs1[(size_t)csr[e] * 64 + l];
                s1[nn][l] = a / fmaxf((float)(e1 - e0), 1.f);
            }
            {
                int e0 = off2[g], e1 = off2[g + 1];
                float a = 0.f;
                int e = e0;
                for (; e + 1 < e1; e += 2) {
                    int nA = csr[e], nB = csr[e + 1];
                    a += hs2[(size_t)nA * 64 + l] + hs2[(size_t)nB * 64 + l];
                }
                if (e < e1) a += hs2[(size_t)csr[e] * 64 + l];
                s2[nn][l] = a / fmaxf((float)(e1 - e0), 1.f);
            }
        }
    }
    __syncthreads();

    int j = tid & 63, ng = tid >> 6;
    float acc[8];
    float bj = ba[j] + bb[j];
#pragma unroll
    for (int ni = 0; ni < 8; ++ni) acc[ni] = bj;
#pragma unroll 4
    for (int k = 0; k < 64; ++k) {
        float w1 = Wl1[k * 64 + j];
        float w2 = Wl2[k * 64 + j];
        float wr = Wr1[k * 64 + j] + Wr2[k * 64 + j];
#pragma unroll
        for (int ni = 0; ni < 8; ++ni) {
            int nn = ng * 8 + ni;
            acc[ni] += s1[nn][k] * w1 + s2[nn][k] * w2 + hd[nn][k] * wr;
        }
    }
    float res[8];
    float brj = bres[j];
#pragma unroll
    for (int ni = 0; ni < 8; ++ni) res[ni] = brj;
#pragma unroll 4
    for (int k = 0; k < 128; ++k) {
        float wv = Wres[k * 64 + j];
#pragma unroll
        for (int ni = 0; ni < 8; ++ni) res[ni] += xd[ng * 8 + ni][k] * wv;
    }
#pragma unroll
    for (int ni = 0; ni < 8; ++ni) {
        int nn = ng * 8 + ni;
        int g = node0 + nn;
        if (g < n) out[(size_t)g * 64 + j] = 0.5f * acc[ni] + res[ni];
    }
}

// row L2 normalization in-place: one wave per 64-wide row
__global__ __launch_bounds__(256) void l2norm_k(float* out, int rows) {
    int gw = (blockIdx.x * 256 + threadIdx.x) >> 6;
    int l = threadIdx.x & 63;
    if (gw >= rows) return;
    float v = out[(size_t)gw * 64 + l];
    float ss = v * v;
#pragma unroll
    for (int m = 1; m < 64; m <<= 1) ss += __shfl_xor(ss, m);
    out[(size_t)gw * 64 + l] = v / fmaxf(sqrtf(ss), 1e-12f);
}

extern "C" void kernel_launch(void* const* d_in, const int* in_sizes, int n_in,
                              void* d_out, int out_size, void* d_ws, size_t ws_size,
                              hipStream_t stream) {
    const float* x_c = (const float*)d_in[0];
    const float* x_m = (const float*)d_in[1];
    const float* x_d = (const float*)d_in[2];
    const int* src_cm = (const int*)d_in[3];
    const int* dst_cm = (const int*)d_in[4];
    const int* src_md = (const int*)d_in[5];
    const int* dst_md = (const int*)d_in[6];
    const int* src_cd = (const int*)d_in[7];
    const int* dst_cd = (const int*)d_in[8];
    const int* src_mc = (const int*)d_in[9];
    const int* dst_mc = (const int*)d_in[10];
    const int* src_dm = (const int*)d_in[11];
    const int* dst_dm = (const int*)d_in[12];
    const int* src_dc = (const int*)d_in[13];
    const int* dst_dc = (const int*)d_in[14];
    const float* W1l = (const float*)d_in[15];  // [6][128][64]
    const float* W1r = (const float*)d_in[16];
    const float* b1 = (const float*)d_in[17];   // [6][64]
    const float* W2l = (const float*)d_in[18];  // [6][64][64]
    const float* W2r = (const float*)d_in[19];
    const float* b2 = (const float*)d_in[20];
    const float* Wres = (const float*)d_in[21]; // [3][128][64]
    const float* bres = (const float*)d_in[22]; // [3][64]
    float* out = (float*)d_out;

    // workspace layout (ints then floats)
    int* off = (int*)d_ws;              // NSLOTS+1 (padded to 320064)
    int* cursor = off + 320064;         // NSLOTS (padded to 320064)
    int* bsum = cursor + 320064;        // 256
    int* csr = bsum + 256;              // 6*EE = 4,800,000
    float* h_c = (float*)(csr + 6 * EE);            // 100000*64
    float* h_m = h_c + (size_t)NC * 64;             // 50000*64
    float* h_d = h_m + (size_t)NM * 64;             // 10000*64

    const int SB0 = 0, SB1 = 50000, SB2 = 60000, SB3 = 70000, SB4 = 170000, SB5 = 220000;
    const int EB = EE / 256;  // 3125
    const int NBS = (NSLOTS + 2047) / 2048;  // 157

    zero_k<<<(NSLOTS + 1 + 255) / 256, 256, 0, stream>>>(off, NSLOTS + 1);

    hist_k<<<EB, 256, 0, stream>>>(dst_cm, off + SB0, EE);
    hist_k<<<EB, 256, 0, stream>>>(dst_md, off + SB1, EE);
    hist_k<<<EB, 256, 0, stream>>>(dst_cd, off + SB2, EE);
    hist_k<<<EB, 256, 0, stream>>>(dst_mc, off + SB3, EE);
    hist_k<<<EB, 256, 0, stream>>>(dst_dm, off + SB4, EE);
    hist_k<<<EB, 256, 0, stream>>>(dst_dc, off + SB5, EE);

    scan_part_k<<<NBS, 256, 0, stream>>>(off, NSLOTS, bsum);
    scan_bsum_k<<<1, 256, 0, stream>>>(bsum, NBS, off, NSLOTS);
    scan_add_k<<<NBS, 256, 0, stream>>>(off, NSLOTS, bsum, cursor);

    scatter_k<<<EB, 256, 0, stream>>>(src_cm, dst_cm, cursor + SB0, csr, EE);
    scatter_k<<<EB, 256, 0, stream>>>(src_md, dst_md, cursor + SB1, csr, EE);
    scatter_k<<<EB, 256, 0, stream>>>(src_cd, dst_cd, cursor + SB2, csr, EE);
    scatter_k<<<EB, 256, 0, stream>>>(src_mc, dst_mc, cursor + SB3, csr, EE);
    scatter_k<<<EB, 256, 0, stream>>>(src_dm, dst_dm, cursor + SB4, csr, EE);
    scatter_k<<<EB, 256, 0, stream>>>(src_dc, dst_dc, cursor + SB5, csr, EE);

    // layer 1: h_m from rel0 (src c) + rel4 (src d); h_d from rel1 (src m) + rel2 (src c);
    //          h_c from rel3 (src m) + rel5 (src d)
    layer1_k<<<(NM + 31) / 32, 256, 0, stream>>>(
        x_c, x_d, x_m, off + SB0, off + SB4, csr,
        W1l + 0 * 8192, W1l + 4 * 8192, W1r + 0 * 8192, W1r + 4 * 8192,
        b1 + 0 * 64, b1 + 4 * 64, h_m, NM);
    layer1_k<<<(ND + 31) / 32, 256, 0, stream>>>(
        x_m, x_c, x_d, off + SB1, off + SB2, csr,
        W1l + 1 * 8192, W1l + 2 * 8192, W1r + 1 * 8192, W1r + 2 * 8192,
        b1 + 1 * 64, b1 + 2 * 64, h_d, ND);
    layer1_k<<<(NC + 31) / 32, 256, 0, stream>>>(
        x_m, x_d, x_c, off + SB3, off + SB5, csr,
        W1l + 3 * 8192, W1l + 5 * 8192, W1r + 3 * 8192, W1r + 5 * 8192,
        b1 + 3 * 64, b1 + 5 * 64, h_c, NC);

    float* out_c = out;
    float* out_m = out + (size_t)NC * 64;
    float* out_d = out_m + (size_t)NM * 64;

    // layer 2 + residual
    layer2_k<<<(NM + 31) / 32, 256, 0, stream>>>(
        h_c, h_d, h_m, x_m, off + SB0, off + SB4, csr,
        W2l + 0 * 4096, W2l + 4 * 4096, W2r + 0 * 4096, W2r + 4 * 4096,
        b2 + 0 * 64, b2 + 4 * 64, Wres + 1 * 8192, bres + 1 * 64, out_m, NM);
    layer2_k<<<(ND + 31) / 32, 256, 0, stream>>>(
        h_m, h_c, h_d, x_d, off + SB1, off + SB2, csr,
        W2l + 1 * 4096, W2l + 2 * 4096, W2r + 1 * 4096, W2r + 2 * 4096,
        b2 + 1 * 64, b2 + 2 * 64, Wres + 2 * 8192, bres + 2 * 64, out_d, ND);
    layer2_k<<<(NC + 31) / 32, 256, 0, stream>>>(
        h_m, h_d, h_c, x_c, off + SB3, off + SB5, csr,
        W2l + 3 * 4096, W2l + 5 * 4096, W2r + 3 * 4096, W2r + 5 * 4096,
        b2 + 3 * 64, b2 + 5 * 64, Wres + 0 * 8192, bres + 0 * 64, out_c, NC);

    // final row L2 normalization over the whole output (160000 rows of 64)
    int rows = NC + NM + ND;
    l2norm_k<<<(rows * 64 + 255) / 256, 256, 0, stream>>>(out, rows);
}

// Round 2
// 1606.658 us; speedup vs baseline: 1.9861x; 1.9861x over previous
//
#include <hip/hip_runtime.h>
#include <cstdint>
#include <cstddef>

#define EE        800000
#define NC        100000
#define NM        50000
#define ND        10000
#define NSLOTS    320000

// relation order: 0=c->m, 1=m->d, 2=c->d, 3=m->c, 4=d->m, 5=d->c
#define SB0 0
#define SB1 50000
#define SB2 60000
#define SB3 70000
#define SB4 170000
#define SB5 220000

__global__ __launch_bounds__(256) void zero_k(int* p, int n) {
    int i = blockIdx.x * 256 + threadIdx.x;
    if (i < n) p[i] = 0;
}

__global__ __launch_bounds__(256) void hist6_k(
    const int* __restrict__ d0, const int* __restrict__ d1, const int* __restrict__ d2,
    const int* __restrict__ d3, const int* __restrict__ d4, const int* __restrict__ d5,
    int* __restrict__ deg)
{
    const int* dst; int base;
    switch (blockIdx.y) {
        case 0: dst = d0; base = SB0; break;
        case 1: dst = d1; base = SB1; break;
        case 2: dst = d2; base = SB2; break;
        case 3: dst = d3; base = SB3; break;
        case 4: dst = d4; base = SB4; break;
        default: dst = d5; base = SB5; break;
    }
    int i = blockIdx.x * 256 + threadIdx.x;
    if (i < EE) atomicAdd(&deg[base + dst[i]], 1);
}

// exclusive scan, 2048 elements per block, in-place; block totals -> bsum
__global__ __launch_bounds__(256) void scan_part_k(int* data, int n, int* bsum) {
    __shared__ int lds[256];
    int tid = threadIdx.x;
    int base = blockIdx.x * 2048 + tid * 8;
    int v[8];
    int tot = 0;
#pragma unroll
    for (int t = 0; t < 8; ++t) {
        int idx = base + t;
        int x = (idx < n) ? data[idx] : 0;
        v[t] = tot;
        tot += x;
    }
    lds[tid] = tot;
    __syncthreads();
    for (int o = 1; o < 256; o <<= 1) {
        int x = 0;
        if (tid >= o) x = lds[tid - o];
        __syncthreads();
        lds[tid] += x;
        __syncthreads();
    }
    int texcl = lds[tid] - tot;
    if (tid == 255) bsum[blockIdx.x] = lds[255];
#pragma unroll
    for (int t = 0; t < 8; ++t) {
        int idx = base + t;
        if (idx < n) data[idx] = texcl + v[t];
    }
}

__global__ __launch_bounds__(256) void scan_bsum_k(int* bsum, int nb, int* data, int n) {
    __shared__ int lds[256];
    int tid = threadIdx.x;
    int x = (tid < nb) ? bsum[tid] : 0;
    lds[tid] = x;
    __syncthreads();
    for (int o = 1; o < 256; o <<= 1) {
        int y = 0;
        if (tid >= o) y = lds[tid - o];
        __syncthreads();
        lds[tid] += y;
        __syncthreads();
    }
    if (tid < nb) bsum[tid] = lds[tid] - x;
    if (tid == 255) data[n] = lds[255];
}

__global__ __launch_bounds__(256) void scan_add_k(int* data, int n, const int* __restrict__ bsum, int* __restrict__ cursor) {
    int base = blockIdx.x * 2048 + threadIdx.x * 8;
    int add = bsum[blockIdx.x];
#pragma unroll
    for (int t = 0; t < 8; ++t) {
        int idx = base + t;
        if (idx < n) {
            int val = data[idx] + add;
            data[idx] = val;
            cursor[idx] = val;
        }
    }
}

__global__ __launch_bounds__(256) void scatter6_k(
    const int* __restrict__ s0, const int* __restrict__ d0,
    const int* __restrict__ s1, const int* __restrict__ d1,
    const int* __restrict__ s2, const int* __restrict__ d2,
    const int* __restrict__ s3, const int* __restrict__ d3,
    const int* __restrict__ s4, const int* __restrict__ d4,
    const int* __restrict__ s5, const int* __restrict__ d5,
    int* __restrict__ cursor, int* __restrict__ csr)
{
    const int* src; const int* dst; int base;
    switch (blockIdx.y) {
        case 0: src = s0; dst = d0; base = SB0; break;
        case 1: src = s1; dst = d1; base = SB1; break;
        case 2: src = s2; dst = d2; base = SB2; break;
        case 3: src = s3; dst = d3; base = SB3; break;
        case 4: src = s4; dst = d4; base = SB4; break;
        default: src = s5; dst = d5; base = SB5; break;
    }
    int i = blockIdx.x * 256 + threadIdx.x;
    if (i < EE) {
        int p = atomicAdd(&cursor[base + dst[i]], 1);
        csr[p] = src[i];
    }
}

__device__ __forceinline__ void fma_nq(float* acc, float4 xv, float4 w0, float4 w1, float4 w2, float4 w3) {
    acc[0] += xv.x * w0.x + xv.y * w1.x + xv.z * w2.x + xv.w * w3.x;
    acc[1] += xv.x * w0.y + xv.y * w1.y + xv.z * w2.y + xv.w * w3.y;
    acc[2] += xv.x * w0.z + xv.y * w1.z + xv.z * w2.z + xv.w * w3.z;
    acc[3] += xv.x * w0.w + xv.y * w1.w + xv.z * w2.w + xv.w * w3.w;
}

// y[n x 64] = x[n x K] @ W[K x 64]
template<int K>
__global__ __launch_bounds__(256) void gemm1_k(const float* __restrict__ x,
    const float* __restrict__ W, float* __restrict__ y, int n)
{
    constexpr int KP = K + 4;          // pad to break LDS bank aliasing
    __shared__ float xs[64 * KP];
    int tid = threadIdx.x;
    int node0 = blockIdx.x * 64;
    constexpr int Q = K / 4;
    for (int idx = tid; idx < 64 * Q; idx += 256) {
        int nn = idx / Q, f4 = idx % Q;
        int g = node0 + nn;
        float4 v = make_float4(0.f, 0.f, 0.f, 0.f);
        if (g < n) v = ((const float4*)x)[(size_t)g * Q + f4];
        *((float4*)(xs + nn * KP + f4 * 4)) = v;
    }
    __syncthreads();
    int jq = tid & 15;       // output col quad (cols jq*4..+3)
    int ng = tid >> 4;       // node group, nodes ng*4..+3
    float acc[4][4] = {};
#pragma unroll 4
    for (int k = 0; k < K; k += 4) {
        float4 wv0 = ((const float4*)(W + (k + 0) * 64))[jq];
        float4 wv1 = ((const float4*)(W + (k + 1) * 64))[jq];
        float4 wv2 = ((const float4*)(W + (k + 2) * 64))[jq];
        float4 wv3 = ((const float4*)(W + (k + 3) * 64))[jq];
#pragma unroll
        for (int i = 0; i < 4; ++i) {
            float4 xv = *((const float4*)(xs + (ng * 4 + i) * KP + k));
            fma_nq(acc[i], xv, wv0, wv1, wv2, wv3);
        }
    }
#pragma unroll
    for (int i = 0; i < 4; ++i) {
        int g = node0 + ng * 4 + i;
        if (g < n) {
            float4 o = make_float4(acc[i][0], acc[i][1], acc[i][2], acc[i][3]);
            ((float4*)(y + (size_t)g * 64))[jq] = o;
        }
    }
}

// z = 0.5*(x @ (Wa+Wb) + ba + bb), K=128
__global__ __launch_bounds__(256) void gemmz1_k(const float* __restrict__ x,
    const float* __restrict__ Wa, const float* __restrict__ Wb,
    const float* __restrict__ ba, const float* __restrict__ bb,
    float* __restrict__ z, int n)
{
    __shared__ float xs[64 * 132];
    int tid = threadIdx.x;
    int node0 = blockIdx.x * 64;
    for (int idx = tid; idx < 64 * 32; idx += 256) {
        int nn = idx >> 5, f4 = idx & 31;
        int g = node0 + nn;
        float4 v = make_float4(0.f, 0.f, 0.f, 0.f);
        if (g < n) v = ((const float4*)x)[(size_t)g * 32 + f4];
        *((float4*)(xs + nn * 132 + f4 * 4)) = v;
    }
    __syncthreads();
    int jq = tid & 15, ng = tid >> 4;
    float4 bva = ((const float4*)ba)[jq];
    float4 bvb = ((const float4*)bb)[jq];
    float acc[4][4];
#pragma unroll
    for (int i = 0; i < 4; ++i) {
        acc[i][0] = 0.5f * (bva.x + bvb.x);
        acc[i][1] = 0.5f * (bva.y + bvb.y);
        acc[i][2] = 0.5f * (bva.z + bvb.z);
        acc[i][3] = 0.5f * (bva.w + bvb.w);
    }
#pragma unroll 4
    for (int k = 0; k < 128; k += 4) {
        float4 wv[4];
#pragma unroll
        for (int kk = 0; kk < 4; ++kk) {
            float4 a = ((const float4*)(Wa + (k + kk) * 64))[jq];
            float4 b = ((const float4*)(Wb + (k + kk) * 64))[jq];
            wv[kk] = make_float4(0.5f * (a.x + b.x), 0.5f * (a.y + b.y),
                                 0.5f * (a.z + b.z), 0.5f * (a.w + b.w));
        }
#pragma unroll
        for (int i = 0; i < 4; ++i) {
            float4 xv = *((const float4*)(xs + (ng * 4 + i) * 132 + k));
            fma_nq(acc[i], xv, wv[0], wv[1], wv[2], wv[3]);
        }
    }
#pragma unroll
    for (int i = 0; i < 4; ++i) {
        int g = node0 + ng * 4 + i;
        if (g < n) {
            float4 o = make_float4(acc[i][0], acc[i][1], acc[i][2], acc[i][3]);
            ((float4*)(z + (size_t)g * 64))[jq] = o;
        }
    }
}

// z2 = 0.5*(h @ (Wa+Wb) + ba + bb) + x @ Wres + bres   (K1=64 over h, K2=128 over x)
__global__ __launch_bounds__(256) void gemmz2_k(
    const float* __restrict__ h, const float* __restrict__ x,
    const float* __restrict__ Wa, const float* __restrict__ Wb,
    const float* __restrict__ ba, const float* __restrict__ bb,
    const float* __restrict__ Wres, const float* __restrict__ bres,
    float* __restrict__ z, int n)
{
    __shared__ float hs[64 * 68];
    __shared__ float xs[64 * 132];
    int tid = threadIdx.x;
    int node0 = blockIdx.x * 64;
    for (int idx = tid; idx < 64 * 16; idx += 256) {
        int nn = idx >> 4, f4 = idx & 15;
        int g = node0 + nn;
        float4 v = make_float4(0.f, 0.f, 0.f, 0.f);
        if (g < n) v = ((const float4*)h)[(size_t)g * 16 + f4];
        *((float4*)(hs + nn * 68 + f4 * 4)) = v;
    }
    for (int idx = tid; idx < 64 * 32; idx += 256) {
        int nn = idx >> 5, f4 = idx & 31;
        int g = node0 + nn;
        float4 v = make_float4(0.f, 0.f, 0.f, 0.f);
        if (g < n) v = ((const float4*)x)[(size_t)g * 32 + f4];
        *((float4*)(xs + nn * 132 + f4 * 4)) = v;
    }
    __syncthreads();
    int jq = tid & 15, ng = tid >> 4;
    float4 bva = ((const float4*)ba)[jq];
    float4 bvb = ((const float4*)bb)[jq];
    float4 bvr = ((const float4*)bres)[jq];
    float acc[4][4];
#pragma unroll
    for (int i = 0; i < 4; ++i) {
        acc[i][0] = 0.5f * (bva.x + bvb.x) + bvr.x;
        acc[i][1] = 0.5f * (bva.y + bvb.y) + bvr.y;
        acc[i][2] = 0.5f * (bva.z + bvb.z) + bvr.z;
        acc[i][3] = 0.5f * (bva.w + bvb.w) + bvr.w;
    }
#pragma unroll 4
    for (int k = 0; k < 64; k += 4) {
        float4 wv[4];
#pragma unroll
        for (int kk = 0; kk < 4; ++kk) {
            float4 a = ((const float4*)(Wa + (k + kk) * 64))[jq];
            float4 b = ((const float4*)(Wb + (k + kk) * 64))[jq];
            wv[kk] = make_float4(0.5f * (a.x + b.x), 0.5f * (a.y + b.y),
                                 0.5f * (a.z + b.z), 0.5f * (a.w + b.w));
        }
#pragma unroll
        for (int i = 0; i < 4; ++i) {
            float4 xv = *((const float4*)(hs + (ng * 4 + i) * 68 + k));
            fma_nq(acc[i], xv, wv[0], wv[1], wv[2], wv[3]);
        }
    }
#pragma unroll 4
    for (int k = 0; k < 128; k += 4) {
        float4 wv0 = ((const float4*)(Wres + (k + 0) * 64))[jq];
        float4 wv1 = ((const float4*)(Wres + (k + 1) * 64))[jq];
        float4 wv2 = ((const float4*)(Wres + (k + 2) * 64))[jq];
        float4 wv3 = ((const float4*)(Wres + (k + 3) * 64))[jq];
#pragma unroll
        for (int i = 0; i < 4; ++i) {
            float4 xv = *((const float4*)(xs + (ng * 4 + i) * 132 + k));
            fma_nq(acc[i], xv, wv0, wv1, wv2, wv3);
        }
    }
#pragma unroll
    for (int i = 0; i < 4; ++i) {
        int g = node0 + ng * 4 + i;
        if (g < n) {
            float4 o = make_float4(acc[i][0], acc[i][1], acc[i][2], acc[i][3]);
            ((float4*)(z + (size_t)g * 64))[jq] = o;
        }
    }
}

// one wave per dst node: out = post(0.5*(mean(y1[csr]) + mean(y2[csr])) + z)
// quarter q of the wave handles edges e0+q, e0+q+4, ... ; each quarter-lane ql
// loads float4 => 16 lanes cover the full 256B row; unroll 2 => ~8 gathers in flight.
template<bool RELU, bool NORM>
__global__ __launch_bounds__(256) void agg_k(
    const float* __restrict__ y1, const float* __restrict__ y2,
    const float* __restrict__ z,
    const int* __restrict__ off1, const int* __restrict__ off2,
    const int* __restrict__ csr, float* __restrict__ outp, int n)
{
    int wid = blockIdx.x * 4 + (threadIdx.x >> 6);
    if (wid >= n) return;
    int lane = threadIdx.x & 63;
    int q = lane >> 4, ql = lane & 15;
    float4 acc = make_float4(0.f, 0.f, 0.f, 0.f);
    {
        int e0 = off1[wid], e1 = off1[wid + 1];
        float4 a = make_float4(0.f, 0.f, 0.f, 0.f);
        int e = e0 + q;
        for (; e + 4 < e1; e += 8) {
            int sA = csr[e], sB = csr[e + 4];
            float4 vA = ((const float4*)(y1 + ((size_t)sA << 6)))[ql];
            float4 vB = ((const float4*)(y1 + ((size_t)sB << 6)))[ql];
            a.x += vA.x + vB.x; a.y += vA.y + vB.y;
            a.z += vA.z + vB.z; a.w += vA.w + vB.w;
        }
        if (e < e1) {
            float4 v = ((const float4*)(y1 + ((size_t)csr[e] << 6)))[ql];
            a.x += v.x; a.y += v.y; a.z += v.z; a.w += v.w;
        }
        float inv = 1.f / fmaxf((float)(e1 - e0), 1.f);
        acc.x += a.x * inv; acc.y += a.y * inv; acc.z += a.z * inv; acc.w += a.w * inv;
    }
    {
        int e0 = off2[wid], e1 = off2[wid + 1];
        float4 a = make_float4(0.f, 0.f, 0.f, 0.f);
        int e = e0 + q;
        for (; e + 4 < e1; e += 8) {
            int sA = csr[e], sB = csr[e + 4];
            float4 vA = ((const float4*)(y2 + ((size_t)sA << 6)))[ql];
            float4 vB = ((const float4*)(y2 + ((size_t)sB << 6)))[ql];
            a.x += vA.x + vB.x; a.y += vA.y + vB.y;
            a.z += vA.z + vB.z; a.w += vA.w + vB.w;
        }
        if (e < e1) {
            float4 v = ((const float4*)(y2 + ((size_t)csr[e] << 6)))[ql];
            a.x += v.x; a.y += v.y; a.z += v.z; a.w += v.w;
        }
        float inv = 1.f / fmaxf((float)(e1 - e0), 1.f);
        acc.x += a.x * inv; acc.y += a.y * inv; acc.z += a.z * inv; acc.w += a.w * inv;
    }
    // combine the 4 quarters
    acc.x += __shfl_xor(acc.x, 16); acc.y += __shfl_xor(acc.y, 16);
    acc.z += __shfl_xor(acc.z, 16); acc.w += __shfl_xor(acc.w, 16);
    acc.x += __shfl_xor(acc.x, 32); acc.y += __shfl_xor(acc.y, 32);
    acc.z += __shfl_xor(acc.z, 32); acc.w += __shfl_xor(acc.w, 32);
    if (q == 0) {
        float4 zz = ((const float4*)(z + ((size_t)wid << 6)))[ql];
        float4 o = make_float4(0.5f * acc.x + zz.x, 0.5f * acc.y + zz.y,
                               0.5f * acc.z + zz.z, 0.5f * acc.w + zz.w);
        if (RELU) {
            o.x = fmaxf(o.x, 0.f); o.y = fmaxf(o.y, 0.f);
            o.z = fmaxf(o.z, 0.f); o.w = fmaxf(o.w, 0.f);
        }
        if (NORM) {
            float ss = o.x * o.x + o.y * o.y + o.z * o.z + o.w * o.w;
            ss += __shfl_xor(ss, 1); ss += __shfl_xor(ss, 2);
            ss += __shfl_xor(ss, 4); ss += __shfl_xor(ss, 8);
            float r = 1.f / fmaxf(sqrtf(ss), 1e-12f);
            o.x *= r; o.y *= r; o.z *= r; o.w *= r;
        }
        ((float4*)(outp + ((size_t)wid << 6)))[ql] = o;
    }
}

extern "C" void kernel_launch(void* const* d_in, const int* in_sizes, int n_in,
                              void* d_out, int out_size, void* d_ws, size_t ws_size,
                              hipStream_t stream) {
    const float* x_c = (const float*)d_in[0];
    const float* x_m = (const float*)d_in[1];
    const float* x_d = (const float*)d_in[2];
    const int* src_cm = (const int*)d_in[3];
    const int* dst_cm = (const int*)d_in[4];
    const int* src_md = (const int*)d_in[5];
    const int* dst_md = (const int*)d_in[6];
    const int* src_cd = (const int*)d_in[7];
    const int* dst_cd = (const int*)d_in[8];
    const int* src_mc = (const int*)d_in[9];
    const int* dst_mc = (const int*)d_in[10];
    const int* src_dm = (const int*)d_in[11];
    const int* dst_dm = (const int*)d_in[12];
    const int* src_dc = (const int*)d_in[13];
    const int* dst_dc = (const int*)d_in[14];
    const float* W1l = (const float*)d_in[15];  // [6][128][64]
    const float* W1r = (const float*)d_in[16];
    const float* b1 = (const float*)d_in[17];   // [6][64]
    const float* W2l = (const float*)d_in[18];  // [6][64][64]
    const float* W2r = (const float*)d_in[19];
    const float* b2 = (const float*)d_in[20];
    const float* Wres = (const float*)d_in[21]; // [3][128][64]
    const float* bres = (const float*)d_in[22]; // [3][64]
    float* out = (float*)d_out;

    // workspace: ints then floats (int region is 16B-aligned in size)
    int* off = (int*)d_ws;              // 320064
    int* cursor = off + 320064;         // 320064
    int* bsum = cursor + 320064;        // 256
    int* csr = bsum + 256;              // 4,800,000
    float* h_c = (float*)(csr + 6 * EE);            // h: 160000*64 floats
    float* h_m = h_c + (size_t)NC * 64;
    float* h_d = h_m + (size_t)NM * 64;
    float* z = h_d + (size_t)ND * 64;               // z: 100000*64 (reused per pass)
    float* y = z + (size_t)NC * 64;                 // y: 150000*64 (reused per pass)

    const int EB = EE / 256;                 // 3125
    const int NBS = (NSLOTS + 2047) / 2048;  // 157

    zero_k<<<(NSLOTS + 1 + 255) / 256, 256, 0, stream>>>(off, NSLOTS + 1);
    hist6_k<<<dim3(EB, 6), 256, 0, stream>>>(dst_cm, dst_md, dst_cd, dst_mc, dst_dm, dst_dc, off);
    scan_part_k<<<NBS, 256, 0, stream>>>(off, NSLOTS, bsum);
    scan_bsum_k<<<1, 256, 0, stream>>>(bsum, NBS, off, NSLOTS);
    scan_add_k<<<NBS, 256, 0, stream>>>(off, NSLOTS, bsum, cursor);
    scatter6_k<<<dim3(EB, 6), 256, 0, stream>>>(src_cm, dst_cm, src_md, dst_md, src_cd, dst_cd,
                                                src_mc, dst_mc, src_dm, dst_dm, src_dc, dst_dc,
                                                cursor, csr);

    float* out_c = out;
    float* out_m = out + (size_t)NC * 64;
    float* out_d = out_m + (size_t)NM * 64;

    // ---------------- layer 1 ----------------
    // m-pass: rel0 (src c) + rel4 (src d)
    {
        float* ya = y;                       // 100k rows (src c)
        float* yb = y + (size_t)NC * 64;     // 10k rows (src d)
        gemm1_k<128><<<(NC + 63) / 64, 256, 0, stream>>>(x_c, W1l + 0 * 8192, ya, NC);
        gemm1_k<128><<<(ND + 63) / 64, 256, 0, stream>>>(x_d, W1l + 4 * 8192, yb, ND);
        gemmz1_k<<<(NM + 63) / 64, 256, 0, stream>>>(x_m, W1r + 0 * 8192, W1r + 4 * 8192,
                                                     b1 + 0 * 64, b1 + 4 * 64, z, NM);
        agg_k<true, false><<<(NM + 3) / 4, 256, 0, stream>>>(ya, yb, z, off + SB0, off + SB4, csr, h_m, NM);
    }
    // d-pass: rel1 (src m) + rel2 (src c)
    {
        float* ya = y;                       // 50k rows (src m)
        float* yb = y + (size_t)NM * 64;     // 100k rows (src c)
        gemm1_k<128><<<(NM + 63) / 64, 256, 0, stream>>>(x_m, W1l + 1 * 8192, ya, NM);
        gemm1_k<128><<<(NC + 63) / 64, 256, 0, stream>>>(x_c, W1l + 2 * 8192, yb, NC);
        gemmz1_k<<<(ND + 63) / 64, 256, 0, stream>>>(x_d, W1r + 1 * 8192, W1r + 2 * 8192,
                                                     b1 + 1 * 64, b1 + 2 * 64, z, ND);
        agg_k<true, false><<<(ND + 3) / 4, 256, 0, stream>>>(ya, yb, z, off + SB1, off + SB2, csr, h_d, ND);
    }
    // c-pass: rel3 (src m) + rel5 (src d)
    {
        float* ya = y;                       // 50k rows (src m)
        float* yb = y + (size_t)NM * 64;     // 10k rows (src d)
        gemm1_k<128><<<(NM + 63) / 64, 256, 0, stream>>>(x_m, W1l + 3 * 8192, ya, NM);
        gemm1_k<128><<<(ND + 63) / 64, 256, 0, stream>>>(x_d, W1l + 5 * 8192, yb, ND);
        gemmz1_k<<<(NC + 63) / 64, 256, 0, stream>>>(x_c, W1r + 3 * 8192, W1r + 5 * 8192,
                                                     b1 + 3 * 64, b1 + 5 * 64, z, NC);
        agg_k<true, false><<<(NC + 3) / 4, 256, 0, stream>>>(ya, yb, z, off + SB3, off + SB5, csr, h_c, NC);
    }

    // ---------------- layer 2 (+res, +l2norm) ----------------
    // m-pass: rel0 (src h_c) + rel4 (src h_d); residual uses Wres[1]
    {
        float* ya = y;
        float* yb = y + (size_t)NC * 64;
        gemm1_k<64><<<(NC + 63) / 64, 256, 0, stream>>>(h_c, W2l + 0 * 4096, ya, NC);
        gemm1_k<64><<<(ND + 63) / 64, 256, 0, stream>>>(h_d, W2l + 4 * 4096, yb, ND);
        gemmz2_k<<<(NM + 63) / 64, 256, 0, stream>>>(h_m, x_m, W2r + 0 * 4096, W2r + 4 * 4096,
                                                     b2 + 0 * 64, b2 + 4 * 64,
                                                     Wres + 1 * 8192, bres + 1 * 64, z, NM);
        agg_k<false, true><<<(NM + 3) / 4, 256, 0, stream>>>(ya, yb, z, off + SB0, off + SB4, csr, out_m, NM);
    }
    // d-pass: rel1 (src h_m) + rel2 (src h_c); residual Wres[2]
    {
        float* ya = y;
        float* yb = y + (size_t)NM * 64;
        gemm1_k<64><<<(NM + 63) / 64, 256, 0, stream>>>(h_m, W2l + 1 * 4096, ya, NM);
        gemm1_k<64><<<(NC + 63) / 64, 256, 0, stream>>>(h_c, W2l + 2 * 4096, yb, NC);
        gemmz2_k<<<(ND + 63) / 64, 256, 0, stream>>>(h_d, x_d, W2r + 1 * 4096, W2r + 2 * 4096,
                                                     b2 + 1 * 64, b2 + 2 * 64,
                                                     Wres + 2 * 8192, bres + 2 * 64, z, ND);
        agg_k<false, true><<<(ND + 3) / 4, 256, 0, stream>>>(ya, yb, z, off + SB1, off + SB2, csr, out_d, ND);
    }
    // c-pass: rel3 (src h_m) + rel5 (src h_d); residual Wres[0]
    {
        float* ya = y;
        float* yb = y + (size_t)NM * 64;
        gemm1_k<64><<<(NM + 63) / 64, 256, 0, stream>>>(h_m, W2l + 3 * 4096, ya, NM);
        gemm1_k<64><<<(ND + 63) / 64, 256, 0, stream>>>(h_d, W2l + 5 * 4096, yb, ND);
        gemmz2_k<<<(NC + 63) / 64, 256, 0, stream>>>(h_c, x_c, W2r + 3 * 4096, W2r + 5 * 4096,
                                                     b2 + 3 * 64, b2 + 5 * 64,
                                                     Wres + 0 * 8192, bres + 0 * 64, z, NC);
        agg_k<false, true><<<(NC + 3) / 4, 256, 0, stream>>>(ya, yb, z, off + SB3, off + SB5, csr, out_c, NC);
    }
}

// Round 3
// 1580.783 us; speedup vs baseline: 2.0186x; 1.0164x over previous
//
#include <hip/hip_runtime.h>
#include <cstdint>
#include <cstddef>

#define EE        800000
#define NC        100000
#define NM        50000
#define ND        10000
#define NSLOTS    320000

// relation order: 0=c->m, 1=m->d, 2=c->d, 3=m->c, 4=d->m, 5=d->c
#define SB0 0
#define SB1 50000
#define SB2 60000
#define SB3 70000
#define SB4 170000
#define SB5 220000

// buckets: 400 per relation, spb slots each => exp. 2000 edges per bucket
// spb per relation: {125, 25, 25, 250, 125, 250}; max slots/bucket = 250
#define NB 2400
#define EPB 4096   // edges per block in hist/partition
#define EBL 196    // ceil(EE/EPB)

__global__ __launch_bounds__(256) void zero_k(int* p, int n) {
    int i = blockIdx.x * 256 + threadIdx.x;
    if (i < n) p[i] = 0;
}

__device__ __forceinline__ int bucket_local(int rel, int dst) {
    switch (rel) {
        case 0: return dst / 125;
        case 1: return dst / 25;
        case 2: return dst / 25;
        case 3: return dst / 250;
        case 4: return dst / 125;
        default: return dst / 250;
    }
}

__global__ __launch_bounds__(256) void bucket_hist_k(
    const int* __restrict__ d0, const int* __restrict__ d1, const int* __restrict__ d2,
    const int* __restrict__ d3, const int* __restrict__ d4, const int* __restrict__ d5,
    int* __restrict__ bhist)
{
    __shared__ int hl[400];
    int rel = blockIdx.y;
    const int* dst;
    switch (rel) {
        case 0: dst = d0; break; case 1: dst = d1; break; case 2: dst = d2; break;
        case 3: dst = d3; break; case 4: dst = d4; break; default: dst = d5; break;
    }
    int tid = threadIdx.x;
    for (int i = tid; i < 400; i += 256) hl[i] = 0;
    __syncthreads();
    int e0 = blockIdx.x * EPB;
#pragma unroll
    for (int t = 0; t < EPB / 256; ++t) {
        int e = e0 + t * 256 + tid;
        if (e < EE) {
            int lb = bucket_local(rel, dst[e]);
            atomicAdd(&hl[lb], 1);
        }
    }
    __syncthreads();
    for (int i = tid; i < 400; i += 256) {
        int v = hl[i];
        if (v) atomicAdd(&bhist[rel * 400 + i], v);
    }
}

// scan 2400 bucket counts -> bOff (exclusive, bOff[NB]=total), copy to bCur,
// and write off[NSLOTS]=6*EE
__global__ __launch_bounds__(256) void bucket_scan_k(const int* __restrict__ bhist,
    int* __restrict__ bOff, int* __restrict__ bCur, int* __restrict__ off)
{
    __shared__ int lds[256];
    int tid = threadIdx.x;
    int v[10];
    int tot = 0;
#pragma unroll
    for (int t = 0; t < 10; ++t) {
        int idx = tid * 10 + t;
        int x = (idx < NB) ? bhist[idx] : 0;
        v[t] = tot;
        tot += x;
    }
    lds[tid] = tot;
    __syncthreads();
    for (int o = 1; o < 256; o <<= 1) {
        int x = 0;
        if (tid >= o) x = lds[tid - o];
        __syncthreads();
        lds[tid] += x;
        __syncthreads();
    }
    int excl = lds[tid] - tot;
#pragma unroll
    for (int t = 0; t < 10; ++t) {
        int idx = tid * 10 + t;
        if (idx < NB) {
            int val = excl + v[t];
            bOff[idx] = val;
            bCur[idx] = val;
        }
    }
    if (tid == 255) {
        bOff[NB] = lds[255];
        off[NSLOTS] = lds[255];   // == 6*EE
    }
}

__global__ __launch_bounds__(256) void partition_k(
    const int* __restrict__ s0, const int* __restrict__ d0,
    const int* __restrict__ s1, const int* __restrict__ d1,
    const int* __restrict__ s2, const int* __restrict__ d2,
    const int* __restrict__ s3, const int* __restrict__ d3,
    const int* __restrict__ s4, const int* __restrict__ d4,
    const int* __restrict__ s5, const int* __restrict__ d5,
    int* __restrict__ bCur, int2* __restrict__ bArr)
{
    int rel = blockIdx.y;
    const int* src; const int* dst;
    switch (rel) {
        case 0: src = s0; dst = d0; break;
        case 1: src = s1; dst = d1; break;
        case 2: src = s2; dst = d2; break;
        case 3: src = s3; dst = d3; break;
        case 4: src = s4; dst = d4; break;
        default: src = s5; dst = d5; break;
    }
    int tid = threadIdx.x;
    int e0 = blockIdx.x * EPB;
#pragma unroll
    for (int t = 0; t < EPB / 256; ++t) {
        int e = e0 + t * 256 + tid;
        if (e < EE) {
            int d = dst[e];
            int b = rel * 400 + bucket_local(rel, d);
            int p = atomicAdd(&bCur[b], 1);
            bArr[p] = make_int2(src[e], d);
        }
    }
}

// one block per bucket: local hist+scan over <=250 slots, write off[], scatter csr[]
__global__ __launch_bounds__(256) void bucket_build_k(
    const int2* __restrict__ bArr, const int* __restrict__ bOff,
    int* __restrict__ off, int* __restrict__ csr)
{
    __shared__ int cnt[256];
    __shared__ int sc[256];
    __shared__ int cur[256];
    int b = blockIdx.x;
    int tid = threadIdx.x;
    int r = b / 400;
    int lb = b - r * 400;
    int spb, sbase;
    switch (r) {
        case 0: spb = 125; sbase = SB0; break;
        case 1: spb = 25;  sbase = SB1; break;
        case 2: spb = 25;  sbase = SB2; break;
        case 3: spb = 250; sbase = SB3; break;
        case 4: spb = 125; sbase = SB4; break;
        default: spb = 250; sbase = SB5; break;
    }
    int slot0 = lb * spb;          // relation-local first slot of this bucket
    int e0 = bOff[b], e1 = bOff[b + 1];

    cnt[tid] = 0;
    __syncthreads();
    for (int e = e0 + tid; e < e1; e += 256) {
        int2 p = bArr[e];
        atomicAdd(&cnt[p.y - slot0], 1);
    }
    __syncthreads();
    int x = cnt[tid];
    sc[tid] = x;
    __syncthreads();
    for (int o = 1; o < 256; o <<= 1) {
        int y = 0;
        if (tid >= o) y = sc[tid - o];
        __syncthreads();
        sc[tid] += y;
        __syncthreads();
    }
    int excl = sc[tid] - x;
    cur[tid] = excl;
    if (tid < spb) off[sbase + slot0 + tid] = e0 + excl;
    __syncthreads();
    for (int e = e0 + tid; e < e1; e += 256) {
        int2 p = bArr[e];
        int pos = atomicAdd(&cur[p.y - slot0], 1);
        csr[e0 + pos] = p.x;
    }
}

__device__ __forceinline__ void fma_nq(float* acc, float4 xv, float4 w0, float4 w1, float4 w2, float4 w3) {
    acc[0] += xv.x * w0.x + xv.y * w1.x + xv.z * w2.x + xv.w * w3.x;
    acc[1] += xv.x * w0.y + xv.y * w1.y + xv.z * w2.y + xv.w * w3.y;
    acc[2] += xv.x * w0.z + xv.y * w1.z + xv.z * w2.z + xv.w * w3.z;
    acc[3] += xv.x * w0.w + xv.y * w1.w + xv.z * w2.w + xv.w * w3.w;
}

// y[n x 64] = x[n x K] @ W[K x 64]
template<int K>
__global__ __launch_bounds__(256) void gemm1_k(const float* __restrict__ x,
    const float* __restrict__ W, float* __restrict__ y, int n)
{
    constexpr int KP = K + 4;
    __shared__ float xs[64 * KP];
    int tid = threadIdx.x;
    int node0 = blockIdx.x * 64;
    constexpr int Q = K / 4;
    for (int idx = tid; idx < 64 * Q; idx += 256) {
        int nn = idx / Q, f4 = idx % Q;
        int g = node0 + nn;
        float4 v = make_float4(0.f, 0.f, 0.f, 0.f);
        if (g < n) v = ((const float4*)x)[(size_t)g * Q + f4];
        *((float4*)(xs + nn * KP + f4 * 4)) = v;
    }
    __syncthreads();
    int jq = tid & 15;
    int ng = tid >> 4;
    float acc[4][4] = {};
#pragma unroll 4
    for (int k = 0; k < K; k += 4) {
        float4 wv0 = ((const float4*)(W + (k + 0) * 64))[jq];
        float4 wv1 = ((const float4*)(W + (k + 1) * 64))[jq];
        float4 wv2 = ((const float4*)(W + (k + 2) * 64))[jq];
        float4 wv3 = ((const float4*)(W + (k + 3) * 64))[jq];
#pragma unroll
        for (int i = 0; i < 4; ++i) {
            float4 xv = *((const float4*)(xs + (ng * 4 + i) * KP + k));
            fma_nq(acc[i], xv, wv0, wv1, wv2, wv3);
        }
    }
#pragma unroll
    for (int i = 0; i < 4; ++i) {
        int g = node0 + ng * 4 + i;
        if (g < n) {
            float4 o = make_float4(acc[i][0], acc[i][1], acc[i][2], acc[i][3]);
            ((float4*)(y + (size_t)g * 64))[jq] = o;
        }
    }
}

// z = 0.5*(x @ (Wa+Wb) + ba + bb), K=128
__global__ __launch_bounds__(256) void gemmz1_k(const float* __restrict__ x,
    const float* __restrict__ Wa, const float* __restrict__ Wb,
    const float* __restrict__ ba, const float* __restrict__ bb,
    float* __restrict__ z, int n)
{
    __shared__ float xs[64 * 132];
    int tid = threadIdx.x;
    int node0 = blockIdx.x * 64;
    for (int idx = tid; idx < 64 * 32; idx += 256) {
        int nn = idx >> 5, f4 = idx & 31;
        int g = node0 + nn;
        float4 v = make_float4(0.f, 0.f, 0.f, 0.f);
        if (g < n) v = ((const float4*)x)[(size_t)g * 32 + f4];
        *((float4*)(xs + nn * 132 + f4 * 4)) = v;
    }
    __syncthreads();
    int jq = tid & 15, ng = tid >> 4;
    float4 bva = ((const float4*)ba)[jq];
    float4 bvb = ((const float4*)bb)[jq];
    float acc[4][4];
#pragma unroll
    for (int i = 0; i < 4; ++i) {
        acc[i][0] = 0.5f * (bva.x + bvb.x);
        acc[i][1] = 0.5f * (bva.y + bvb.y);
        acc[i][2] = 0.5f * (bva.z + bvb.z);
        acc[i][3] = 0.5f * (bva.w + bvb.w);
    }
#pragma unroll 4
    for (int k = 0; k < 128; k += 4) {
        float4 wv[4];
#pragma unroll
        for (int kk = 0; kk < 4; ++kk) {
            float4 a = ((const float4*)(Wa + (k + kk) * 64))[jq];
            float4 b = ((const float4*)(Wb + (k + kk) * 64))[jq];
            wv[kk] = make_float4(0.5f * (a.x + b.x), 0.5f * (a.y + b.y),
                                 0.5f * (a.z + b.z), 0.5f * (a.w + b.w));
        }
#pragma unroll
        for (int i = 0; i < 4; ++i) {
            float4 xv = *((const float4*)(xs + (ng * 4 + i) * 132 + k));
            fma_nq(acc[i], xv, wv[0], wv[1], wv[2], wv[3]);
        }
    }
#pragma unroll
    for (int i = 0; i < 4; ++i) {
        int g = node0 + ng * 4 + i;
        if (g < n) {
            float4 o = make_float4(acc[i][0], acc[i][1], acc[i][2], acc[i][3]);
            ((float4*)(z + (size_t)g * 64))[jq] = o;
        }
    }
}

// z2 = 0.5*(h @ (Wa+Wb) + ba + bb) + x @ Wres + bres
__global__ __launch_bounds__(256) void gemmz2_k(
    const float* __restrict__ h, const float* __restrict__ x,
    const float* __restrict__ Wa, const float* __restrict__ Wb,
    const float* __restrict__ ba, const float* __restrict__ bb,
    const float* __restrict__ Wres, const float* __restrict__ bres,
    float* __restrict__ z, int n)
{
    __shared__ float hs[64 * 68];
    __shared__ float xs[64 * 132];
    int tid = threadIdx.x;
    int node0 = blockIdx.x * 64;
    for (int idx = tid; idx < 64 * 16; idx += 256) {
        int nn = idx >> 4, f4 = idx & 15;
        int g = node0 + nn;
        float4 v = make_float4(0.f, 0.f, 0.f, 0.f);
        if (g < n) v = ((const float4*)h)[(size_t)g * 16 + f4];
        *((float4*)(hs + nn * 68 + f4 * 4)) = v;
    }
    for (int idx = tid; idx < 64 * 32; idx += 256) {
        int nn = idx >> 5, f4 = idx & 31;
        int g = node0 + nn;
        float4 v = make_float4(0.f, 0.f, 0.f, 0.f);
        if (g < n) v = ((const float4*)x)[(size_t)g * 32 + f4];
        *((float4*)(xs + nn * 132 + f4 * 4)) = v;
    }
    __syncthreads();
    int jq = tid & 15, ng = tid >> 4;
    float4 bva = ((const float4*)ba)[jq];
    float4 bvb = ((const float4*)bb)[jq];
    float4 bvr = ((const float4*)bres)[jq];
    float acc[4][4];
#pragma unroll
    for (int i = 0; i < 4; ++i) {
        acc[i][0] = 0.5f * (bva.x + bvb.x) + bvr.x;
        acc[i][1] = 0.5f * (bva.y + bvb.y) + bvr.y;
        acc[i][2] = 0.5f * (bva.z + bvb.z) + bvr.z;
        acc[i][3] = 0.5f * (bva.w + bvb.w) + bvr.w;
    }
#pragma unroll 4
    for (int k = 0; k < 64; k += 4) {
        float4 wv[4];
#pragma unroll
        for (int kk = 0; kk < 4; ++kk) {
            float4 a = ((const float4*)(Wa + (k + kk) * 64))[jq];
            float4 b = ((const float4*)(Wb + (k + kk) * 64))[jq];
            wv[kk] = make_float4(0.5f * (a.x + b.x), 0.5f * (a.y + b.y),
                                 0.5f * (a.z + b.z), 0.5f * (a.w + b.w));
        }
#pragma unroll
        for (int i = 0; i < 4; ++i) {
            float4 xv = *((const float4*)(hs + (ng * 4 + i) * 68 + k));
            fma_nq(acc[i], xv, wv[0], wv[1], wv[2], wv[3]);
        }
    }
#pragma unroll 4
    for (int k = 0; k < 128; k += 4) {
        float4 wv0 = ((const float4*)(Wres + (k + 0) * 64))[jq];
        float4 wv1 = ((const float4*)(Wres + (k + 1) * 64))[jq];
        float4 wv2 = ((const float4*)(Wres + (k + 2) * 64))[jq];
        float4 wv3 = ((const float4*)(Wres + (k + 3) * 64))[jq];
#pragma unroll
        for (int i = 0; i < 4; ++i) {
            float4 xv = *((const float4*)(xs + (ng * 4 + i) * 132 + k));
            fma_nq(acc[i], xv, wv0, wv1, wv2, wv3);
        }
    }
#pragma unroll
    for (int i = 0; i < 4; ++i) {
        int g = node0 + ng * 4 + i;
        if (g < n) {
            float4 o = make_float4(acc[i][0], acc[i][1], acc[i][2], acc[i][3]);
            ((float4*)(z + (size_t)g * 64))[jq] = o;
        }
    }
}

// one wave per dst node: out = post(0.5*(mean(y1[csr]) + mean(y2[csr])) + z)
template<bool RELU, bool NORM>
__global__ __launch_bounds__(256) void agg_k(
    const float* __restrict__ y1, const float* __restrict__ y2,
    const float* __restrict__ z,
    const int* __restrict__ off1, const int* __restrict__ off2,
    const int* __restrict__ csr, float* __restrict__ outp, int n)
{
    int wid = blockIdx.x * 4 + (threadIdx.x >> 6);
    if (wid >= n) return;
    int lane = threadIdx.x & 63;
    int q = lane >> 4, ql = lane & 15;
    float4 acc = make_float4(0.f, 0.f, 0.f, 0.f);
    {
        int e0 = off1[wid], e1 = off1[wid + 1];
        float4 a = make_float4(0.f, 0.f, 0.f, 0.f);
        int e = e0 + q;
        for (; e + 4 < e1; e += 8) {
            int sA = csr[e], sB = csr[e + 4];
            float4 vA = ((const float4*)(y1 + ((size_t)sA << 6)))[ql];
            float4 vB = ((const float4*)(y1 + ((size_t)sB << 6)))[ql];
            a.x += vA.x + vB.x; a.y += vA.y + vB.y;
            a.z += vA.z + vB.z; a.w += vA.w + vB.w;
        }
        if (e < e1) {
            float4 v = ((const float4*)(y1 + ((size_t)csr[e] << 6)))[ql];
            a.x += v.x; a.y += v.y; a.z += v.z; a.w += v.w;
        }
        float inv = 1.f / fmaxf((float)(e1 - e0), 1.f);
        acc.x += a.x * inv; acc.y += a.y * inv; acc.z += a.z * inv; acc.w += a.w * inv;
    }
    {
        int e0 = off2[wid], e1 = off2[wid + 1];
        float4 a = make_float4(0.f, 0.f, 0.f, 0.f);
        int e = e0 + q;
        for (; e + 4 < e1; e += 8) {
            int sA = csr[e], sB = csr[e + 4];
            float4 vA = ((const float4*)(y2 + ((size_t)sA << 6)))[ql];
            float4 vB = ((const float4*)(y2 + ((size_t)sB << 6)))[ql];
            a.x += vA.x + vB.x; a.y += vA.y + vB.y;
            a.z += vA.z + vB.z; a.w += vA.w + vB.w;
        }
        if (e < e1) {
            float4 v = ((const float4*)(y2 + ((size_t)csr[e] << 6)))[ql];
            a.x += v.x; a.y += v.y; a.z += v.z; a.w += v.w;
        }
        float inv = 1.f / fmaxf((float)(e1 - e0), 1.f);
        acc.x += a.x * inv; acc.y += a.y * inv; acc.z += a.z * inv; acc.w += a.w * inv;
    }
    acc.x += __shfl_xor(acc.x, 16); acc.y += __shfl_xor(acc.y, 16);
    acc.z += __shfl_xor(acc.z, 16); acc.w += __shfl_xor(acc.w, 16);
    acc.x += __shfl_xor(acc.x, 32); acc.y += __shfl_xor(acc.y, 32);
    acc.z += __shfl_xor(acc.z, 32); acc.w += __shfl_xor(acc.w, 32);
    if (q == 0) {
        float4 zz = ((const float4*)(z + ((size_t)wid << 6)))[ql];
        float4 o = make_float4(0.5f * acc.x + zz.x, 0.5f * acc.y + zz.y,
                               0.5f * acc.z + zz.z, 0.5f * acc.w + zz.w);
        if (RELU) {
            o.x = fmaxf(o.x, 0.f); o.y = fmaxf(o.y, 0.f);
            o.z = fmaxf(o.z, 0.f); o.w = fmaxf(o.w, 0.f);
        }
        if (NORM) {
            float ss = o.x * o.x + o.y * o.y + o.z * o.z + o.w * o.w;
            ss += __shfl_xor(ss, 1); ss += __shfl_xor(ss, 2);
            ss += __shfl_xor(ss, 4); ss += __shfl_xor(ss, 8);
            float r = 1.f / fmaxf(sqrtf(ss), 1e-12f);
            o.x *= r; o.y *= r; o.z *= r; o.w *= r;
        }
        ((float4*)(outp + ((size_t)wid << 6)))[ql] = o;
    }
}

extern "C" void kernel_launch(void* const* d_in, const int* in_sizes, int n_in,
                              void* d_out, int out_size, void* d_ws, size_t ws_size,
                              hipStream_t stream) {
    const float* x_c = (const float*)d_in[0];
    const float* x_m = (const float*)d_in[1];
    const float* x_d = (const float*)d_in[2];
    const int* src_cm = (const int*)d_in[3];
    const int* dst_cm = (const int*)d_in[4];
    const int* src_md = (const int*)d_in[5];
    const int* dst_md = (const int*)d_in[6];
    const int* src_cd = (const int*)d_in[7];
    const int* dst_cd = (const int*)d_in[8];
    const int* src_mc = (const int*)d_in[9];
    const int* dst_mc = (const int*)d_in[10];
    const int* src_dm = (const int*)d_in[11];
    const int* dst_dm = (const int*)d_in[12];
    const int* src_dc = (const int*)d_in[13];
    const int* dst_dc = (const int*)d_in[14];
    const float* W1l = (const float*)d_in[15];  // [6][128][64]
    const float* W1r = (const float*)d_in[16];
    const float* b1 = (const float*)d_in[17];   // [6][64]
    const float* W2l = (const float*)d_in[18];  // [6][64][64]
    const float* W2r = (const float*)d_in[19];
    const float* b2 = (const float*)d_in[20];
    const float* Wres = (const float*)d_in[21]; // [3][128][64]
    const float* bres = (const float*)d_in[22]; // [3][64]
    float* out = (float*)d_out;

    // workspace layout
    int* off = (int*)d_ws;                       // 320064 ints (320001 used)
    int* csr = off + 320064;                     // 4,800,000 ints
    int* bhist = csr + 6 * EE;                   // 2400
    int* bOff = bhist + 2400;                    // 2401 (pad 2404)
    int* bCur = bOff + 2404;                     // 2400 (pad 2404)
    float* h_c = (float*)(bCur + 2404);          // h: 160000*64 floats
    float* h_m = h_c + (size_t)NC * 64;
    float* h_d = h_m + (size_t)NM * 64;
    float* z = h_d + (size_t)ND * 64;            // z: 100000*64 floats
    float* y = z + (size_t)NC * 64;              // y: 9.6M floats, aliased w/ bArr
    int2* bArr = (int2*)y;                       // 4.8M int2 == 9.6M floats

    // ---- CSR build (bucketed) ----
    zero_k<<<(NB + 255) / 256, 256, 0, stream>>>(bhist, NB);
    bucket_hist_k<<<dim3(EBL, 6), 256, 0, stream>>>(dst_cm, dst_md, dst_cd, dst_mc, dst_dm, dst_dc, bhist);
    bucket_scan_k<<<1, 256, 0, stream>>>(bhist, bOff, bCur, off);
    partition_k<<<dim3(EBL, 6), 256, 0, stream>>>(src_cm, dst_cm, src_md, dst_md, src_cd, dst_cd,
                                                  src_mc, dst_mc, src_dm, dst_dm, src_dc, dst_dc,
                                                  bCur, bArr);
    bucket_build_k<<<NB, 256, 0, stream>>>(bArr, bOff, off, csr);

    float* out_c = out;
    float* out_m = out + (size_t)NC * 64;
    float* out_d = out_m + (size_t)NM * 64;

    // ---------------- layer 1 ----------------
    {   // m-pass: rel0 (src c) + rel4 (src d)
        float* ya = y;
        float* yb = y + (size_t)NC * 64;
        gemm1_k<128><<<(NC + 63) / 64, 256, 0, stream>>>(x_c, W1l + 0 * 8192, ya, NC);
        gemm1_k<128><<<(ND + 63) / 64, 256, 0, stream>>>(x_d, W1l + 4 * 8192, yb, ND);
        gemmz1_k<<<(NM + 63) / 64, 256, 0, stream>>>(x_m, W1r + 0 * 8192, W1r + 4 * 8192,
                                                     b1 + 0 * 64, b1 + 4 * 64, z, NM);
        agg_k<true, false><<<(NM + 3) / 4, 256, 0, stream>>>(ya, yb, z, off + SB0, off + SB4, csr, h_m, NM);
    }
    {   // d-pass: rel1 (src m) + rel2 (src c)
        float* ya = y;
        float* yb = y + (size_t)NM * 64;
        gemm1_k<128><<<(NM + 63) / 64, 256, 0, stream>>>(x_m, W1l + 1 * 8192, ya, NM);
        gemm1_k<128><<<(NC + 63) / 64, 256, 0, stream>>>(x_c, W1l + 2 * 8192, yb, NC);
        gemmz1_k<<<(ND + 63) / 64, 256, 0, stream>>>(x_d, W1r + 1 * 8192, W1r + 2 * 8192,
                                                     b1 + 1 * 64, b1 + 2 * 64, z, ND);
        agg_k<true, false><<<(ND + 3) / 4, 256, 0, stream>>>(ya, yb, z, off + SB1, off + SB2, csr, h_d, ND);
    }
    {   // c-pass: rel3 (src m) + rel5 (src d)
        float* ya = y;
        float* yb = y + (size_t)NM * 64;
        gemm1_k<128><<<(NM + 63) / 64, 256, 0, stream>>>(x_m, W1l + 3 * 8192, ya, NM);
        gemm1_k<128><<<(ND + 63) / 64, 256, 0, stream>>>(x_d, W1l + 5 * 8192, yb, ND);
        gemmz1_k<<<(NC + 63) / 64, 256, 0, stream>>>(x_c, W1r + 3 * 8192, W1r + 5 * 8192,
                                                     b1 + 3 * 64, b1 + 5 * 64, z, NC);
        agg_k<true, false><<<(NC + 3) / 4, 256, 0, stream>>>(ya, yb, z, off + SB3, off + SB5, csr, h_c, NC);
    }

    // ---------------- layer 2 (+res, +l2norm) ----------------
    {   // m-pass
        float* ya = y;
        float* yb = y + (size_t)NC * 64;
        gemm1_k<64><<<(NC + 63) / 64, 256, 0, stream>>>(h_c, W2l + 0 * 4096, ya, NC);
        gemm1_k<64><<<(ND + 63) / 64, 256, 0, stream>>>(h_d, W2l + 4 * 4096, yb, ND);
        gemmz2_k<<<(NM + 63) / 64, 256, 0, stream>>>(h_m, x_m, W2r + 0 * 4096, W2r + 4 * 4096,
                                                     b2 + 0 * 64, b2 + 4 * 64,
                                                     Wres + 1 * 8192, bres + 1 * 64, z, NM);
        agg_k<false, true><<<(NM + 3) / 4, 256, 0, stream>>>(ya, yb, z, off + SB0, off + SB4, csr, out_m, NM);
    }
    {   // d-pass
        float* ya = y;
        float* yb = y + (size_t)NM * 64;
        gemm1_k<64><<<(NM + 63) / 64, 256, 0, stream>>>(h_m, W2l + 1 * 4096, ya, NM);
        gemm1_k<64><<<(NC + 63) / 64, 256, 0, stream>>>(h_c, W2l + 2 * 4096, yb, NC);
        gemmz2_k<<<(ND + 63) / 64, 256, 0, stream>>>(h_d, x_d, W2r + 1 * 4096, W2r + 2 * 4096,
                                                     b2 + 1 * 64, b2 + 2 * 64,
                                                     Wres + 2 * 8192, bres + 2 * 64, z, ND);
        agg_k<false, true><<<(ND + 3) / 4, 256, 0, stream>>>(ya, yb, z, off + SB1, off + SB2, csr, out_d, ND);
    }
    {   // c-pass
        float* ya = y;
        float* yb = y + (size_t)NM * 64;
        gemm1_k<64><<<(NM + 63) / 64, 256, 0, stream>>>(h_m, W2l + 3 * 4096, ya, NM);
        gemm1_k<64><<<(ND + 63) / 64, 256, 0, stream>>>(h_d, W2l + 5 * 4096, yb, ND);
        gemmz2_k<<<(NC + 63) / 64, 256, 0, stream>>>(h_c, x_c, W2r + 3 * 4096, W2r + 5 * 4096,
                                                     b2 + 3 * 64, b2 + 5 * 64,
                                                     Wres + 0 * 8192, bres + 0 * 64, z, NC);
        agg_k<false, true><<<(NC + 3) / 4, 256, 0, stream>>>(ya, yb, z, off + SB3, off + SB5, csr, out_c, NC);
    }
}

// Round 4
// 1282.865 us; speedup vs baseline: 2.4874x; 1.2322x over previous
//
#include <hip/hip_runtime.h>
#include <cstdint>
#include <cstddef>

#define EE        800000
#define NC        100000
#define NM        50000
#define ND        10000
#define NSLOTS    320000

// relation order: 0=c->m, 1=m->d, 2=c->d, 3=m->c, 4=d->m, 5=d->c
#define SB0 0
#define SB1 50000
#define SB2 60000
#define SB3 70000
#define SB4 170000
#define SB5 220000

// buckets: 400 per relation, spb slots each => exp. 2000 edges per bucket
// spb per relation: {125, 25, 25, 250, 125, 250}; max slots/bucket = 250
#define NB 2400
#define EPB 4096    // edges per block in hist
#define EBL 196     // ceil(EE/EPB)
#define EPB2 16384  // edges per block in partition
#define PBL 49      // ceil(EE/EPB2)
#define BCAP 3072   // LDS staging capacity in bucket_build

__global__ __launch_bounds__(256) void zero_k(int* p, int n) {
    int i = blockIdx.x * 256 + threadIdx.x;
    if (i < n) p[i] = 0;
}

__device__ __forceinline__ int bucket_local(int rel, int dst) {
    switch (rel) {
        case 0: return dst / 125;
        case 1: return dst / 25;
        case 2: return dst / 25;
        case 3: return dst / 250;
        case 4: return dst / 125;
        default: return dst / 250;
    }
}

__global__ __launch_bounds__(256) void bucket_hist_k(
    const int* __restrict__ d0, const int* __restrict__ d1, const int* __restrict__ d2,
    const int* __restrict__ d3, const int* __restrict__ d4, const int* __restrict__ d5,
    int* __restrict__ bhist)
{
    __shared__ int hl[400];
    int rel = blockIdx.y;
    const int* dst;
    switch (rel) {
        case 0: dst = d0; break; case 1: dst = d1; break; case 2: dst = d2; break;
        case 3: dst = d3; break; case 4: dst = d4; break; default: dst = d5; break;
    }
    int tid = threadIdx.x;
    for (int i = tid; i < 400; i += 256) hl[i] = 0;
    __syncthreads();
    int e0 = blockIdx.x * EPB;
#pragma unroll
    for (int t = 0; t < EPB / 256; ++t) {
        int e = e0 + t * 256 + tid;
        if (e < EE) {
            int lb = bucket_local(rel, dst[e]);
            atomicAdd(&hl[lb], 1);
        }
    }
    __syncthreads();
    for (int i = tid; i < 400; i += 256) {
        int v = hl[i];
        if (v) atomicAdd(&bhist[rel * 400 + i], v);
    }
}

// scan 2400 bucket counts -> bOff (exclusive, bOff[NB]=total), copy to bCur,
// and write off[NSLOTS]=6*EE
__global__ __launch_bounds__(256) void bucket_scan_k(const int* __restrict__ bhist,
    int* __restrict__ bOff, int* __restrict__ bCur, int* __restrict__ off)
{
    __shared__ int lds[256];
    int tid = threadIdx.x;
    int v[10];
    int tot = 0;
#pragma unroll
    for (int t = 0; t < 10; ++t) {
        int idx = tid * 10 + t;
        int x = (idx < NB) ? bhist[idx] : 0;
        v[t] = tot;
        tot += x;
    }
    lds[tid] = tot;
    __syncthreads();
    for (int o = 1; o < 256; o <<= 1) {
        int x = 0;
        if (tid >= o) x = lds[tid - o];
        __syncthreads();
        lds[tid] += x;
        __syncthreads();
    }
    int excl = lds[tid] - tot;
#pragma unroll
    for (int t = 0; t < 10; ++t) {
        int idx = tid * 10 + t;
        if (idx < NB) {
            int val = excl + v[t];
            bOff[idx] = val;
            bCur[idx] = val;
        }
    }
    if (tid == 255) {
        bOff[NB] = lds[255];
        off[NSLOTS] = lds[255];   // == 6*EE
    }
}

// two-pass multi-split with BLOCK-PRIVATE bucket chunk reservation:
// pass A: LDS histogram of this block's 16384 edges; one global atomicAdd per
// non-empty bucket reserves a contiguous private chunk; pass B scatters via
// LDS cursors. Every csr-region line is written by (almost) one block only.
__global__ __launch_bounds__(256) void partition_k(
    const int* __restrict__ s0, const int* __restrict__ d0,
    const int* __restrict__ s1, const int* __restrict__ d1,
    const int* __restrict__ s2, const int* __restrict__ d2,
    const int* __restrict__ s3, const int* __restrict__ d3,
    const int* __restrict__ s4, const int* __restrict__ d4,
    const int* __restrict__ s5, const int* __restrict__ d5,
    int* __restrict__ bCur, int2* __restrict__ bArr)
{
    __shared__ int hist[400];
    __shared__ int curs[400];
    int rel = blockIdx.y;
    const int* src; const int* dst;
    switch (rel) {
        case 0: src = s0; dst = d0; break;
        case 1: src = s1; dst = d1; break;
        case 2: src = s2; dst = d2; break;
        case 3: src = s3; dst = d3; break;
        case 4: src = s4; dst = d4; break;
        default: src = s5; dst = d5; break;
    }
    int tid = threadIdx.x;
    for (int i = tid; i < 400; i += 256) hist[i] = 0;
    __syncthreads();
    int e0 = blockIdx.x * EPB2;
    int e1 = e0 + EPB2; if (e1 > EE) e1 = EE;
    for (int e = e0 + tid; e < e1; e += 256) {
        int lb = bucket_local(rel, dst[e]);
        atomicAdd(&hist[lb], 1);
    }
    __syncthreads();
    for (int i = tid; i < 400; i += 256) {
        int c = hist[i];
        curs[i] = c ? atomicAdd(&bCur[rel * 400 + i], c) : 0;
    }
    __syncthreads();
    for (int e = e0 + tid; e < e1; e += 256) {
        int d = dst[e];
        int lb = bucket_local(rel, d);
        int p = atomicAdd(&curs[lb], 1);
        bArr[p] = make_int2(src[e], d);
    }
}

// one block per bucket: stage edges in LDS, local hist+scan over <=250 slots,
// write off[], scatter csr[] into the block's contiguous region
__global__ __launch_bounds__(256) void bucket_build_k(
    const int2* __restrict__ bArr, const int* __restrict__ bOff,
    int* __restrict__ off, int* __restrict__ csr)
{
    __shared__ int cnt[256];
    __shared__ int sc[256];
    __shared__ int cur[256];
    __shared__ int2 stage[BCAP];
    int b = blockIdx.x;
    int tid = threadIdx.x;
    int r = b / 400;
    int lb = b - r * 400;
    int spb, sbase;
    switch (r) {
        case 0: spb = 125; sbase = SB0; break;
        case 1: spb = 25;  sbase = SB1; break;
        case 2: spb = 25;  sbase = SB2; break;
        case 3: spb = 250; sbase = SB3; break;
        case 4: spb = 125; sbase = SB4; break;
        default: spb = 250; sbase = SB5; break;
    }
    int slot0 = lb * spb;
    int e0 = bOff[b], e1 = bOff[b + 1];
    int m = e1 - e0;
    int ms = m < BCAP ? m : BCAP;

    cnt[tid] = 0;
    __syncthreads();
    for (int i = tid; i < ms; i += 256) {
        int2 p = bArr[e0 + i];
        stage[i] = p;
        atomicAdd(&cnt[p.y - slot0], 1);
    }
    for (int i = BCAP + tid; i < m; i += 256) {     // overflow tail (rare)
        int2 p = bArr[e0 + i];
        atomicAdd(&cnt[p.y - slot0], 1);
    }
    __syncthreads();
    int x = cnt[tid];
    sc[tid] = x;
    __syncthreads();
    for (int o = 1; o < 256; o <<= 1) {
        int y = 0;
        if (tid >= o) y = sc[tid - o];
        __syncthreads();
        sc[tid] += y;
        __syncthreads();
    }
    int excl = sc[tid] - x;
    cur[tid] = excl;
    if (tid < spb) off[sbase + slot0 + tid] = e0 + excl;
    __syncthreads();
    for (int i = tid; i < ms; i += 256) {
        int2 p = stage[i];
        int pos = atomicAdd(&cur[p.y - slot0], 1);
        csr[e0 + pos] = p.x;
    }
    for (int i = BCAP + tid; i < m; i += 256) {
        int2 p = bArr[e0 + i];
        int pos = atomicAdd(&cur[p.y - slot0], 1);
        csr[e0 + pos] = p.x;
    }
}

__device__ __forceinline__ void fma_nq(float* acc, float4 xv, float4 w0, float4 w1, float4 w2, float4 w3) {
    acc[0] += xv.x * w0.x + xv.y * w1.x + xv.z * w2.x + xv.w * w3.x;
    acc[1] += xv.x * w0.y + xv.y * w1.y + xv.z * w2.y + xv.w * w3.y;
    acc[2] += xv.x * w0.z + xv.y * w1.z + xv.z * w2.z + xv.w * w3.z;
    acc[3] += xv.x * w0.w + xv.y * w1.w + xv.z * w2.w + xv.w * w3.w;
}

// y[n x 64] = x[n x K] @ W[K x 64]
template<int K>
__global__ __launch_bounds__(256) void gemm1_k(const float* __restrict__ x,
    const float* __restrict__ W, float* __restrict__ y, int n)
{
    constexpr int KP = K + 4;
    __shared__ float xs[64 * KP];
    int tid = threadIdx.x;
    int node0 = blockIdx.x * 64;
    constexpr int Q = K / 4;
    for (int idx = tid; idx < 64 * Q; idx += 256) {
        int nn = idx / Q, f4 = idx % Q;
        int g = node0 + nn;
        float4 v = make_float4(0.f, 0.f, 0.f, 0.f);
        if (g < n) v = ((const float4*)x)[(size_t)g * Q + f4];
        *((float4*)(xs + nn * KP + f4 * 4)) = v;
    }
    __syncthreads();
    int jq = tid & 15;
    int ng = tid >> 4;
    float acc[4][4] = {};
#pragma unroll 4
    for (int k = 0; k < K; k += 4) {
        float4 wv0 = ((const float4*)(W + (k + 0) * 64))[jq];
        float4 wv1 = ((const float4*)(W + (k + 1) * 64))[jq];
        float4 wv2 = ((const float4*)(W + (k + 2) * 64))[jq];
        float4 wv3 = ((const float4*)(W + (k + 3) * 64))[jq];
#pragma unroll
        for (int i = 0; i < 4; ++i) {
            float4 xv = *((const float4*)(xs + (ng * 4 + i) * KP + k));
            fma_nq(acc[i], xv, wv0, wv1, wv2, wv3);
        }
    }
#pragma unroll
    for (int i = 0; i < 4; ++i) {
        int g = node0 + ng * 4 + i;
        if (g < n) {
            float4 o = make_float4(acc[i][0], acc[i][1], acc[i][2], acc[i][3]);
            ((float4*)(y + (size_t)g * 64))[jq] = o;
        }
    }
}

// z = 0.5*(x @ (Wa+Wb) + ba + bb), K=128
__global__ __launch_bounds__(256) void gemmz1_k(const float* __restrict__ x,
    const float* __restrict__ Wa, const float* __restrict__ Wb,
    const float* __restrict__ ba, const float* __restrict__ bb,
    float* __restrict__ z, int n)
{
    __shared__ float xs[64 * 132];
    int tid = threadIdx.x;
    int node0 = blockIdx.x * 64;
    for (int idx = tid; idx < 64 * 32; idx += 256) {
        int nn = idx >> 5, f4 = idx & 31;
        int g = node0 + nn;
        float4 v = make_float4(0.f, 0.f, 0.f, 0.f);
        if (g < n) v = ((const float4*)x)[(size_t)g * 32 + f4];
        *((float4*)(xs + nn * 132 + f4 * 4)) = v;
    }
    __syncthreads();
    int jq = tid & 15, ng = tid >> 4;
    float4 bva = ((const float4*)ba)[jq];
    float4 bvb = ((const float4*)bb)[jq];
    float acc[4][4];
#pragma unroll
    for (int i = 0; i < 4; ++i) {
        acc[i][0] = 0.5f * (bva.x + bvb.x);
        acc[i][1] = 0.5f * (bva.y + bvb.y);
        acc[i][2] = 0.5f * (bva.z + bvb.z);
        acc[i][3] = 0.5f * (bva.w + bvb.w);
    }
#pragma unroll 4
    for (int k = 0; k < 128; k += 4) {
        float4 wv[4];
#pragma unroll
        for (int kk = 0; kk < 4; ++kk) {
            float4 a = ((const float4*)(Wa + (k + kk) * 64))[jq];
            float4 b = ((const float4*)(Wb + (k + kk) * 64))[jq];
            wv[kk] = make_float4(0.5f * (a.x + b.x), 0.5f * (a.y + b.y),
                                 0.5f * (a.z + b.z), 0.5f * (a.w + b.w));
        }
#pragma unroll
        for (int i = 0; i < 4; ++i) {
            float4 xv = *((const float4*)(xs + (ng * 4 + i) * 132 + k));
            fma_nq(acc[i], xv, wv[0], wv[1], wv[2], wv[3]);
        }
    }
#pragma unroll
    for (int i = 0; i < 4; ++i) {
        int g = node0 + ng * 4 + i;
        if (g < n) {
            float4 o = make_float4(acc[i][0], acc[i][1], acc[i][2], acc[i][3]);
            ((float4*)(z + (size_t)g * 64))[jq] = o;
        }
    }
}

// z2 = 0.5*(h @ (Wa+Wb) + ba + bb) + x @ Wres + bres
__global__ __launch_bounds__(256) void gemmz2_k(
    const float* __restrict__ h, const float* __restrict__ x,
    const float* __restrict__ Wa, const float* __restrict__ Wb,
    const float* __restrict__ ba, const float* __restrict__ bb,
    const float* __restrict__ Wres, const float* __restrict__ bres,
    float* __restrict__ z, int n)
{
    __shared__ float hs[64 * 68];
    __shared__ float xs[64 * 132];
    int tid = threadIdx.x;
    int node0 = blockIdx.x * 64;
    for (int idx = tid; idx < 64 * 16; idx += 256) {
        int nn = idx >> 4, f4 = idx & 15;
        int g = node0 + nn;
        float4 v = make_float4(0.f, 0.f, 0.f, 0.f);
        if (g < n) v = ((const float4*)h)[(size_t)g * 16 + f4];
        *((float4*)(hs + nn * 68 + f4 * 4)) = v;
    }
    for (int idx = tid; idx < 64 * 32; idx += 256) {
        int nn = idx >> 5, f4 = idx & 31;
        int g = node0 + nn;
        float4 v = make_float4(0.f, 0.f, 0.f, 0.f);
        if (g < n) v = ((const float4*)x)[(size_t)g * 32 + f4];
        *((float4*)(xs + nn * 132 + f4 * 4)) = v;
    }
    __syncthreads();
    int jq = tid & 15, ng = tid >> 4;
    float4 bva = ((const float4*)ba)[jq];
    float4 bvb = ((const float4*)bb)[jq];
    float4 bvr = ((const float4*)bres)[jq];
    float acc[4][4];
#pragma unroll
    for (int i = 0; i < 4; ++i) {
        acc[i][0] = 0.5f * (bva.x + bvb.x) + bvr.x;
        acc[i][1] = 0.5f * (bva.y + bvb.y) + bvr.y;
        acc[i][2] = 0.5f * (bva.z + bvb.z) + bvr.z;
        acc[i][3] = 0.5f * (bva.w + bvb.w) + bvr.w;
    }
#pragma unroll 4
    for (int k = 0; k < 64; k += 4) {
        float4 wv[4];
#pragma unroll
        for (int kk = 0; kk < 4; ++kk) {
            float4 a = ((const float4*)(Wa + (k + kk) * 64))[jq];
            float4 b = ((const float4*)(Wb + (k + kk) * 64))[jq];
            wv[kk] = make_float4(0.5f * (a.x + b.x), 0.5f * (a.y + b.y),
                                 0.5f * (a.z + b.z), 0.5f * (a.w + b.w));
        }
#pragma unroll
        for (int i = 0; i < 4; ++i) {
            float4 xv = *((const float4*)(hs + (ng * 4 + i) * 68 + k));
            fma_nq(acc[i], xv, wv[0], wv[1], wv[2], wv[3]);
        }
    }
#pragma unroll 4
    for (int k = 0; k < 128; k += 4) {
        float4 wv0 = ((const float4*)(Wres + (k + 0) * 64))[jq];
        float4 wv1 = ((const float4*)(Wres + (k + 1) * 64))[jq];
        float4 wv2 = ((const float4*)(Wres + (k + 2) * 64))[jq];
        float4 wv3 = ((const float4*)(Wres + (k + 3) * 64))[jq];
#pragma unroll
        for (int i = 0; i < 4; ++i) {
            float4 xv = *((const float4*)(xs + (ng * 4 + i) * 132 + k));
            fma_nq(acc[i], xv, wv0, wv1, wv2, wv3);
        }
    }
#pragma unroll
    for (int i = 0; i < 4; ++i) {
        int g = node0 + ng * 4 + i;
        if (g < n) {
            float4 o = make_float4(acc[i][0], acc[i][1], acc[i][2], acc[i][3]);
            ((float4*)(z + (size_t)g * 64))[jq] = o;
        }
    }
}

// one wave per dst node: out = post(0.5*(mean(y1[csr]) + mean(y2[csr])) + z)
template<bool RELU, bool NORM>
__global__ __launch_bounds__(256) void agg_k(
    const float* __restrict__ y1, const float* __restrict__ y2,
    const float* __restrict__ z,
    const int* __restrict__ off1, const int* __restrict__ off2,
    const int* __restrict__ csr, float* __restrict__ outp, int n)
{
    int wid = blockIdx.x * 4 + (threadIdx.x >> 6);
    if (wid >= n) return;
    int lane = threadIdx.x & 63;
    int q = lane >> 4, ql = lane & 15;
    float4 acc = make_float4(0.f, 0.f, 0.f, 0.f);
    {
        int e0 = off1[wid], e1 = off1[wid + 1];
        float4 a = make_float4(0.f, 0.f, 0.f, 0.f);
        int e = e0 + q;
        for (; e + 4 < e1; e += 8) {
            int sA = csr[e], sB = csr[e + 4];
            float4 vA = ((const float4*)(y1 + ((size_t)sA << 6)))[ql];
            float4 vB = ((const float4*)(y1 + ((size_t)sB << 6)))[ql];
            a.x += vA.x + vB.x; a.y += vA.y + vB.y;
            a.z += vA.z + vB.z; a.w += vA.w + vB.w;
        }
        if (e < e1) {
            float4 v = ((const float4*)(y1 + ((size_t)csr[e] << 6)))[ql];
            a.x += v.x; a.y += v.y; a.z += v.z; a.w += v.w;
        }
        float inv = 1.f / fmaxf((float)(e1 - e0), 1.f);
        acc.x += a.x * inv; acc.y += a.y * inv; acc.z += a.z * inv; acc.w += a.w * inv;
    }
    {
        int e0 = off2[wid], e1 = off2[wid + 1];
        float4 a = make_float4(0.f, 0.f, 0.f, 0.f);
        int e = e0 + q;
        for (; e + 4 < e1; e += 8) {
            int sA = csr[e], sB = csr[e + 4];
            float4 vA = ((const float4*)(y2 + ((size_t)sA << 6)))[ql];
            float4 vB = ((const float4*)(y2 + ((size_t)sB << 6)))[ql];
            a.x += vA.x + vB.x; a.y += vA.y + vB.y;
            a.z += vA.z + vB.z; a.w += vA.w + vB.w;
        }
        if (e < e1) {
            float4 v = ((const float4*)(y2 + ((size_t)csr[e] << 6)))[ql];
            a.x += v.x; a.y += v.y; a.z += v.z; a.w += v.w;
        }
        float inv = 1.f / fmaxf((float)(e1 - e0), 1.f);
        acc.x += a.x * inv; acc.y += a.y * inv; acc.z += a.z * inv; acc.w += a.w * inv;
    }
    acc.x += __shfl_xor(acc.x, 16); acc.y += __shfl_xor(acc.y, 16);
    acc.z += __shfl_xor(acc.z, 16); acc.w += __shfl_xor(acc.w, 16);
    acc.x += __shfl_xor(acc.x, 32); acc.y += __shfl_xor(acc.y, 32);
    acc.z += __shfl_xor(acc.z, 32); acc.w += __shfl_xor(acc.w, 32);
    if (q == 0) {
        float4 zz = ((const float4*)(z + ((size_t)wid << 6)))[ql];
        float4 o = make_float4(0.5f * acc.x + zz.x, 0.5f * acc.y + zz.y,
                               0.5f * acc.z + zz.z, 0.5f * acc.w + zz.w);
        if (RELU) {
            o.x = fmaxf(o.x, 0.f); o.y = fmaxf(o.y, 0.f);
            o.z = fmaxf(o.z, 0.f); o.w = fmaxf(o.w, 0.f);
        }
        if (NORM) {
            float ss = o.x * o.x + o.y * o.y + o.z * o.z + o.w * o.w;
            ss += __shfl_xor(ss, 1); ss += __shfl_xor(ss, 2);
            ss += __shfl_xor(ss, 4); ss += __shfl_xor(ss, 8);
            float r = 1.f / fmaxf(sqrtf(ss), 1e-12f);
            o.x *= r; o.y *= r; o.z *= r; o.w *= r;
        }
        ((float4*)(outp + ((size_t)wid << 6)))[ql] = o;
    }
}

extern "C" void kernel_launch(void* const* d_in, const int* in_sizes, int n_in,
                              void* d_out, int out_size, void* d_ws, size_t ws_size,
                              hipStream_t stream) {
    const float* x_c = (const float*)d_in[0];
    const float* x_m = (const float*)d_in[1];
    const float* x_d = (const float*)d_in[2];
    const int* src_cm = (const int*)d_in[3];
    const int* dst_cm = (const int*)d_in[4];
    const int* src_md = (const int*)d_in[5];
    const int* dst_md = (const int*)d_in[6];
    const int* src_cd = (const int*)d_in[7];
    const int* dst_cd = (const int*)d_in[8];
    const int* src_mc = (const int*)d_in[9];
    const int* dst_mc = (const int*)d_in[10];
    const int* src_dm = (const int*)d_in[11];
    const int* dst_dm = (const int*)d_in[12];
    const int* src_dc = (const int*)d_in[13];
    const int* dst_dc = (const int*)d_in[14];
    const float* W1l = (const float*)d_in[15];  // [6][128][64]
    const float* W1r = (const float*)d_in[16];
    const float* b1 = (const float*)d_in[17];   // [6][64]
    const float* W2l = (const float*)d_in[18];  // [6][64][64]
    const float* W2r = (const float*)d_in[19];
    const float* b2 = (const float*)d_in[20];
    const float* Wres = (const float*)d_in[21]; // [3][128][64]
    const float* bres = (const float*)d_in[22]; // [3][64]
    float* out = (float*)d_out;

    // workspace layout
    int* off = (int*)d_ws;                       // 320064 ints
    int* csr = off + 320064;                     // 4,800,000 ints
    int* bhist = csr + 6 * EE;                   // 2400
    int* bOff = bhist + 2400;                    // 2401 (pad 2404)
    int* bCur = bOff + 2404;                     // 2400 (pad 2404)
    float* h_c = (float*)(bCur + 2404);          // h: 160000*64 floats
    float* h_m = h_c + (size_t)NC * 64;
    float* h_d = h_m + (size_t)NM * 64;
    float* z = h_d + (size_t)ND * 64;            // z: 100000*64 floats
    float* y = z + (size_t)NC * 64;              // y: 9.6M floats, aliased w/ bArr
    int2* bArr = (int2*)y;                       // 4.8M int2 == 9.6M floats

    // ---- CSR build (bucketed, block-private chunks) ----
    zero_k<<<(NB + 255) / 256, 256, 0, stream>>>(bhist, NB);
    bucket_hist_k<<<dim3(EBL, 6), 256, 0, stream>>>(dst_cm, dst_md, dst_cd, dst_mc, dst_dm, dst_dc, bhist);
    bucket_scan_k<<<1, 256, 0, stream>>>(bhist, bOff, bCur, off);
    partition_k<<<dim3(PBL, 6), 256, 0, stream>>>(src_cm, dst_cm, src_md, dst_md, src_cd, dst_cd,
                                                  src_mc, dst_mc, src_dm, dst_dm, src_dc, dst_dc,
                                                  bCur, bArr);
    bucket_build_k<<<NB, 256, 0, stream>>>(bArr, bOff, off, csr);

    float* out_c = out;
    float* out_m = out + (size_t)NC * 64;
    float* out_d = out_m + (size_t)NM * 64;

    // ---------------- layer 1 ----------------
    {   // m-pass: rel0 (src c) + rel4 (src d)
        float* ya = y;
        float* yb = y + (size_t)NC * 64;
        gemm1_k<128><<<(NC + 63) / 64, 256, 0, stream>>>(x_c, W1l + 0 * 8192, ya, NC);
        gemm1_k<128><<<(ND + 63) / 64, 256, 0, stream>>>(x_d, W1l + 4 * 8192, yb, ND);
        gemmz1_k<<<(NM + 63) / 64, 256, 0, stream>>>(x_m, W1r + 0 * 8192, W1r + 4 * 8192,
                                                     b1 + 0 * 64, b1 + 4 * 64, z, NM);
        agg_k<true, false><<<(NM + 3) / 4, 256, 0, stream>>>(ya, yb, z, off + SB0, off + SB4, csr, h_m, NM);
    }
    {   // d-pass: rel1 (src m) + rel2 (src c)
        float* ya = y;
        float* yb = y + (size_t)NM * 64;
        gemm1_k<128><<<(NM + 63) / 64, 256, 0, stream>>>(x_m, W1l + 1 * 8192, ya, NM);
        gemm1_k<128><<<(NC + 63) / 64, 256, 0, stream>>>(x_c, W1l + 2 * 8192, yb, NC);
        gemmz1_k<<<(ND + 63) / 64, 256, 0, stream>>>(x_d, W1r + 1 * 8192, W1r + 2 * 8192,
                                                     b1 + 1 * 64, b1 + 2 * 64, z, ND);
        agg_k<true, false><<<(ND + 3) / 4, 256, 0, stream>>>(ya, yb, z, off + SB1, off + SB2, csr, h_d, ND);
    }
    {   // c-pass: rel3 (src m) + rel5 (src d)
        float* ya = y;
        float* yb = y + (size_t)NM * 64;
        gemm1_k<128><<<(NM + 63) / 64, 256, 0, stream>>>(x_m, W1l + 3 * 8192, ya, NM);
        gemm1_k<128><<<(ND + 63) / 64, 256, 0, stream>>>(x_d, W1l + 5 * 8192, yb, ND);
        gemmz1_k<<<(NC + 63) / 64, 256, 0, stream>>>(x_c, W1r + 3 * 8192, W1r + 5 * 8192,
                                                     b1 + 3 * 64, b1 + 5 * 64, z, NC);
        agg_k<true, false><<<(NC + 3) / 4, 256, 0, stream>>>(ya, yb, z, off + SB3, off + SB5, csr, h_c, NC);
    }

    // ---------------- layer 2 (+res, +l2norm) ----------------
    {   // m-pass
        float* ya = y;
        float* yb = y + (size_t)NC * 64;
        gemm1_k<64><<<(NC + 63) / 64, 256, 0, stream>>>(h_c, W2l + 0 * 4096, ya, NC);
        gemm1_k<64><<<(ND + 63) / 64, 256, 0, stream>>>(h_d, W2l + 4 * 4096, yb, ND);
        gemmz2_k<<<(NM + 63) / 64, 256, 0, stream>>>(h_m, x_m, W2r + 0 * 4096, W2r + 4 * 4096,
                                                     b2 + 0 * 64, b2 + 4 * 64,
                                                     Wres + 1 * 8192, bres + 1 * 64, z, NM);
        agg_k<false, true><<<(NM + 3) / 4, 256, 0, stream>>>(ya, yb, z, off + SB0, off + SB4, csr, out_m, NM);
    }
    {   // d-pass
        float* ya = y;
        float* yb = y + (size_t)NM * 64;
        gemm1_k<64><<<(NM + 63) / 64, 256, 0, stream>>>(h_m, W2l + 1 * 4096, ya, NM);
        gemm1_k<64><<<(NC + 63) / 64, 256, 0, stream>>>(h_c, W2l + 2 * 4096, yb, NC);
        gemmz2_k<<<(ND + 63) / 64, 256, 0, stream>>>(h_d, x_d, W2r + 1 * 4096, W2r + 2 * 4096,
                                                     b2 + 1 * 64, b2 + 2 * 64,
                                                     Wres + 2 * 8192, bres + 2 * 64, z, ND);
        agg_k<false, true><<<(ND + 3) / 4, 256, 0, stream>>>(ya, yb, z, off + SB1, off + SB2, csr, out_d, ND);
    }
    {   // c-pass
        float* ya = y;
        float* yb = y + (size_t)NM * 64;
        gemm1_k<64><<<(NM + 63) / 64, 256, 0, stream>>>(h_m, W2l + 3 * 4096, ya, NM);
        gemm1_k<64><<<(ND + 63) / 64, 256, 0, stream>>>(h_d, W2l + 5 * 4096, yb, ND);
        gemmz2_k<<<(NC + 63) / 64, 256, 0, stream>>>(h_c, x_c, W2r + 3 * 4096, W2r + 5 * 4096,
                                                     b2 + 3 * 64, b2 + 5 * 64,
                                                     Wres + 0 * 8192, bres + 0 * 64, z, NC);
        agg_k<false, true><<<(NC + 3) / 4, 256, 0, stream>>>(ya, yb, z, off + SB3, off + SB5, csr, out_c, NC);
    }
}

// Round 5
// 1046.878 us; speedup vs baseline: 3.0481x; 1.2254x over previous
//
#include <hip/hip_runtime.h>
#include <cstdint>
#include <cstddef>

#define EE        800000
#define NC        100000
#define NM        50000
#define ND        10000
#define NSLOTS    320000

// relation order: 0=c->m, 1=m->d, 2=c->d, 3=m->c, 4=d->m, 5=d->c
#define SB0 0
#define SB1 50000
#define SB2 60000
#define SB3 70000
#define SB4 170000
#define SB5 220000

// y_all row offsets per relation (src-transformed tables)
#define R0 0
#define R1 100000
#define R2 150000
#define R3 250000
#define R4 300000
#define R5 310000

// buckets: 400/relation; spb: {125,25,25,250,125,250}
#define NB 2400
#define EPB 4096    // edges/block in hist
#define EBL 196
#define EPB2 8192   // edges/block in partition
#define PBL 98
#define BCAP 3072

__global__ __launch_bounds__(256) void zero_k(int* p, int n) {
    int i = blockIdx.x * 256 + threadIdx.x;
    if (i < n) p[i] = 0;
}

__device__ __forceinline__ void bucket_split(int rel, int d, int& lb, int& dl) {
    switch (rel) {
        case 0: case 4: lb = d / 125; dl = d - lb * 125; break;
        case 1: case 2: lb = d / 25;  dl = d - lb * 25;  break;
        default:        lb = d / 250; dl = d - lb * 250; break;
    }
}

__global__ __launch_bounds__(256) void bucket_hist_k(
    const int* __restrict__ d0, const int* __restrict__ d1, const int* __restrict__ d2,
    const int* __restrict__ d3, const int* __restrict__ d4, const int* __restrict__ d5,
    int* __restrict__ bhist)
{
    __shared__ int hl[400];
    int rel = blockIdx.y;
    const int* dst;
    switch (rel) {
        case 0: dst = d0; break; case 1: dst = d1; break; case 2: dst = d2; break;
        case 3: dst = d3; break; case 4: dst = d4; break; default: dst = d5; break;
    }
    int tid = threadIdx.x;
    for (int i = tid; i < 400; i += 256) hl[i] = 0;
    __syncthreads();
    int e0 = blockIdx.x * EPB;
#pragma unroll
    for (int t = 0; t < EPB / 256; ++t) {
        int e = e0 + t * 256 + tid;
        if (e < EE) {
            int lb, dl;
            bucket_split(rel, dst[e], lb, dl);
            atomicAdd(&hl[lb], 1);
        }
    }
    __syncthreads();
    for (int i = tid; i < 400; i += 256) {
        int v = hl[i];
        if (v) atomicAdd(&bhist[rel * 400 + i], v);
    }
}

__global__ __launch_bounds__(256) void bucket_scan_k(const int* __restrict__ bhist,
    int* __restrict__ bOff, int* __restrict__ bCur, int* __restrict__ off)
{
    __shared__ int lds[256];
    int tid = threadIdx.x;
    int v[10];
    int tot = 0;
#pragma unroll
    for (int t = 0; t < 10; ++t) {
        int idx = tid * 10 + t;
        int x = (idx < NB) ? bhist[idx] : 0;
        v[t] = tot;
        tot += x;
    }
    lds[tid] = tot;
    __syncthreads();
    for (int o = 1; o < 256; o <<= 1) {
        int x = 0;
        if (tid >= o) x = lds[tid - o];
        __syncthreads();
        lds[tid] += x;
        __syncthreads();
    }
    int excl = lds[tid] - tot;
#pragma unroll
    for (int t = 0; t < 10; ++t) {
        int idx = tid * 10 + t;
        if (idx < NB) {
            int val = excl + v[t];
            bOff[idx] = val;
            bCur[idx] = val;
        }
    }
    if (tid == 255) {
        bOff[NB] = lds[255];
        off[NSLOTS] = lds[255];
    }
}

// block-private chunk reservation; packed payload = (dstLocal<<17)|src
__global__ __launch_bounds__(512) void partition_k(
    const int* __restrict__ s0, const int* __restrict__ d0,
    const int* __restrict__ s1, const int* __restrict__ d1,
    const int* __restrict__ s2, const int* __restrict__ d2,
    const int* __restrict__ s3, const int* __restrict__ d3,
    const int* __restrict__ s4, const int* __restrict__ d4,
    const int* __restrict__ s5, const int* __restrict__ d5,
    int* __restrict__ bCur, int* __restrict__ bArr)
{
    __shared__ int hist[400];
    __shared__ int curs[400];
    __shared__ unsigned short lbs[EPB2];
    __shared__ unsigned char dls[EPB2];
    int rel = blockIdx.y;
    const int* src; const int* dst;
    switch (rel) {
        case 0: src = s0; dst = d0; break;
        case 1: src = s1; dst = d1; break;
        case 2: src = s2; dst = d2; break;
        case 3: src = s3; dst = d3; break;
        case 4: src = s4; dst = d4; break;
        default: src = s5; dst = d5; break;
    }
    int tid = threadIdx.x;
    for (int i = tid; i < 400; i += 512) hist[i] = 0;
    __syncthreads();
    int e0 = blockIdx.x * EPB2;
    int e1 = e0 + EPB2; if (e1 > EE) e1 = EE;
    int m = e1 - e0;
    for (int i = tid; i < m; i += 512) {
        int lb, dl;
        bucket_split(rel, dst[e0 + i], lb, dl);
        lbs[i] = (unsigned short)lb;
        dls[i] = (unsigned char)dl;
        atomicAdd(&hist[lb], 1);
    }
    __syncthreads();
    for (int i = tid; i < 400; i += 512) {
        int c = hist[i];
        curs[i] = c ? atomicAdd(&bCur[rel * 400 + i], c) : 0;
    }
    __syncthreads();
    for (int i = tid; i < m; i += 512) {
        int p = atomicAdd(&curs[lbs[i]], 1);
        bArr[p] = ((int)dls[i] << 17) | src[e0 + i];
    }
}

// one block per bucket: LDS stage, hist+scan, write off[], scatter csr[]
__global__ __launch_bounds__(256) void bucket_build_k(
    const int* __restrict__ bArr, const int* __restrict__ bOff,
    int* __restrict__ off, int* __restrict__ csr)
{
    __shared__ int cnt[256];
    __shared__ int sc[256];
    __shared__ int cur[256];
    __shared__ int stage[BCAP];
    int b = blockIdx.x;
    int tid = threadIdx.x;
    int r = b / 400;
    int lb = b - r * 400;
    int spb, sbase;
    switch (r) {
        case 0: spb = 125; sbase = SB0; break;
        case 1: spb = 25;  sbase = SB1; break;
        case 2: spb = 25;  sbase = SB2; break;
        case 3: spb = 250; sbase = SB3; break;
        case 4: spb = 125; sbase = SB4; break;
        default: spb = 250; sbase = SB5; break;
    }
    int slot0 = lb * spb;
    int e0 = bOff[b], e1 = bOff[b + 1];
    int m = e1 - e0;
    int ms = m < BCAP ? m : BCAP;

    cnt[tid] = 0;
    __syncthreads();
    for (int i = tid; i < ms; i += 256) {
        int p = bArr[e0 + i];
        stage[i] = p;
        atomicAdd(&cnt[p >> 17], 1);
    }
    for (int i = BCAP + tid; i < m; i += 256) {
        int p = bArr[e0 + i];
        atomicAdd(&cnt[p >> 17], 1);
    }
    __syncthreads();
    int x = cnt[tid];
    sc[tid] = x;
    __syncthreads();
    for (int o = 1; o < 256; o <<= 1) {
        int y = 0;
        if (tid >= o) y = sc[tid - o];
        __syncthreads();
        sc[tid] += y;
        __syncthreads();
    }
    int excl = sc[tid] - x;
    cur[tid] = excl;
    if (tid < spb) off[sbase + slot0 + tid] = e0 + excl;
    __syncthreads();
    for (int i = tid; i < ms; i += 256) {
        int p = stage[i];
        int pos = atomicAdd(&cur[p >> 17], 1);
        csr[e0 + pos] = p & 0x1FFFF;
    }
    for (int i = BCAP + tid; i < m; i += 256) {
        int p = bArr[e0 + i];
        int pos = atomicAdd(&cur[p >> 17], 1);
        csr[e0 + pos] = p & 0x1FFFF;
    }
}

__device__ __forceinline__ void fma_nq(float* acc, float4 xv, float4 w0, float4 w1, float4 w2, float4 w3) {
    acc[0] += xv.x * w0.x + xv.y * w1.x + xv.z * w2.x + xv.w * w3.x;
    acc[1] += xv.x * w0.y + xv.y * w1.y + xv.z * w2.y + xv.w * w3.y;
    acc[2] += xv.x * w0.z + xv.y * w1.z + xv.z * w2.z + xv.w * w3.z;
    acc[3] += xv.x * w0.w + xv.y * w1.w + xv.z * w2.w + xv.w * w3.w;
}

// all-6-relation y GEMM: y[rowOff+g] = feat_src(r)[g] @ Wl[r]
// block prefix: c:1563, m:782 blocks, d:157; order rel0..rel5
template<int K>
__global__ __launch_bounds__(256) void gemmy_all_k(
    const float* __restrict__ fc, const float* __restrict__ fm, const float* __restrict__ fd,
    const float* __restrict__ Wl, float* __restrict__ y)
{
    int b = blockIdx.x;
    int r, lb;
    if (b < 1563)      { r = 0; lb = b; }
    else if (b < 2345) { r = 1; lb = b - 1563; }
    else if (b < 3908) { r = 2; lb = b - 2345; }
    else if (b < 4690) { r = 3; lb = b - 3908; }
    else if (b < 4847) { r = 4; lb = b - 4690; }
    else               { r = 5; lb = b - 4847; }
    const float* x; int n; int rowOff;
    switch (r) {
        case 0: x = fc; n = NC; rowOff = R0; break;
        case 1: x = fm; n = NM; rowOff = R1; break;
        case 2: x = fc; n = NC; rowOff = R2; break;
        case 3: x = fm; n = NM; rowOff = R3; break;
        case 4: x = fd; n = ND; rowOff = R4; break;
        default: x = fd; n = ND; rowOff = R5; break;
    }
    const float* W = Wl + (size_t)r * K * 64;
    float* yo = y + (size_t)rowOff * 64;

    constexpr int KP = K + 4;
    __shared__ float xs[64 * KP];
    int tid = threadIdx.x;
    int node0 = lb * 64;
    constexpr int Q = K / 4;
    for (int idx = tid; idx < 64 * Q; idx += 256) {
        int nn = idx / Q, f4 = idx % Q;
        int g = node0 + nn;
        float4 v = make_float4(0.f, 0.f, 0.f, 0.f);
        if (g < n) v = ((const float4*)x)[(size_t)g * Q + f4];
        *((float4*)(xs + nn * KP + f4 * 4)) = v;
    }
    __syncthreads();
    int jq = tid & 15, ng = tid >> 4;
    float acc[4][4] = {};
#pragma unroll 4
    for (int k = 0; k < K; k += 4) {
        float4 wv0 = ((const float4*)(W + (k + 0) * 64))[jq];
        float4 wv1 = ((const float4*)(W + (k + 1) * 64))[jq];
        float4 wv2 = ((const float4*)(W + (k + 2) * 64))[jq];
        float4 wv3 = ((const float4*)(W + (k + 3) * 64))[jq];
#pragma unroll
        for (int i = 0; i < 4; ++i) {
            float4 xv = *((const float4*)(xs + (ng * 4 + i) * KP + k));
            fma_nq(acc[i], xv, wv0, wv1, wv2, wv3);
        }
    }
#pragma unroll
    for (int i = 0; i < 4; ++i) {
        int g = node0 + ng * 4 + i;
        if (g < n) {
            float4 o = make_float4(acc[i][0], acc[i][1], acc[i][2], acc[i][3]);
            ((float4*)(yo + (size_t)g * 64))[jq] = o;
        }
    }
}

// L1 z into h (in-place target of agg): z = 0.5*(x@(Wa+Wb)+ba+bb); K=128
// type order m,d,c; block prefix {782, 939, 2502}
__global__ __launch_bounds__(256) void gemmz1_all_k(
    const float* __restrict__ fc, const float* __restrict__ fm, const float* __restrict__ fd,
    const float* __restrict__ W1r, const float* __restrict__ b1,
    float* __restrict__ hc, float* __restrict__ hm, float* __restrict__ hd)
{
    int b = blockIdx.x;
    int t, lb;
    if (b < 782)      { t = 0; lb = b; }
    else if (b < 939) { t = 1; lb = b - 782; }
    else              { t = 2; lb = b - 939; }
    const float* x; int n; const float *Wa, *Wb, *ba, *bb; float* zo;
    switch (t) {
        case 0: x = fm; n = NM; Wa = W1r + 0 * 8192; Wb = W1r + 4 * 8192; ba = b1 + 0 * 64; bb = b1 + 4 * 64; zo = hm; break;
        case 1: x = fd; n = ND; Wa = W1r + 1 * 8192; Wb = W1r + 2 * 8192; ba = b1 + 1 * 64; bb = b1 + 2 * 64; zo = hd; break;
        default: x = fc; n = NC; Wa = W1r + 3 * 8192; Wb = W1r + 5 * 8192; ba = b1 + 3 * 64; bb = b1 + 5 * 64; zo = hc; break;
    }
    __shared__ float xs[64 * 132];
    int tid = threadIdx.x;
    int node0 = lb * 64;
    for (int idx = tid; idx < 64 * 32; idx += 256) {
        int nn = idx >> 5, f4 = idx & 31;
        int g = node0 + nn;
        float4 v = make_float4(0.f, 0.f, 0.f, 0.f);
        if (g < n) v = ((const float4*)x)[(size_t)g * 32 + f4];
        *((float4*)(xs + nn * 132 + f4 * 4)) = v;
    }
    __syncthreads();
    int jq = tid & 15, ng = tid >> 4;
    float4 bva = ((const float4*)ba)[jq];
    float4 bvb = ((const float4*)bb)[jq];
    float acc[4][4];
#pragma unroll
    for (int i = 0; i < 4; ++i) {
        acc[i][0] = 0.5f * (bva.x + bvb.x);
        acc[i][1] = 0.5f * (bva.y + bvb.y);
        acc[i][2] = 0.5f * (bva.z + bvb.z);
        acc[i][3] = 0.5f * (bva.w + bvb.w);
    }
#pragma unroll 4
    for (int k = 0; k < 128; k += 4) {
        float4 wv[4];
#pragma unroll
        for (int kk = 0; kk < 4; ++kk) {
            float4 a = ((const float4*)(Wa + (k + kk) * 64))[jq];
            float4 b2_ = ((const float4*)(Wb + (k + kk) * 64))[jq];
            wv[kk] = make_float4(0.5f * (a.x + b2_.x), 0.5f * (a.y + b2_.y),
                                 0.5f * (a.z + b2_.z), 0.5f * (a.w + b2_.w));
        }
#pragma unroll
        for (int i = 0; i < 4; ++i) {
            float4 xv = *((const float4*)(xs + (ng * 4 + i) * 132 + k));
            fma_nq(acc[i], xv, wv[0], wv[1], wv[2], wv[3]);
        }
    }
#pragma unroll
    for (int i = 0; i < 4; ++i) {
        int g = node0 + ng * 4 + i;
        if (g < n) {
            float4 o = make_float4(acc[i][0], acc[i][1], acc[i][2], acc[i][3]);
            ((float4*)(zo + (size_t)g * 64))[jq] = o;
        }
    }
}

// L2 z into out: z = 0.5*(h@(Wa+Wb)+ba+bb) + x@Wres + bres
__global__ __launch_bounds__(256) void gemmz2_all_k(
    const float* __restrict__ hc, const float* __restrict__ hm, const float* __restrict__ hd,
    const float* __restrict__ xc, const float* __restrict__ xm, const float* __restrict__ xd,
    const float* __restrict__ W2r, const float* __restrict__ b2,
    const float* __restrict__ Wres, const float* __restrict__ bres,
    float* __restrict__ oc, float* __restrict__ om, float* __restrict__ od)
{
    int b = blockIdx.x;
    int t, lb;
    if (b < 782)      { t = 0; lb = b; }
    else if (b < 939) { t = 1; lb = b - 782; }
    else              { t = 2; lb = b - 939; }
    const float *h, *x; int n; const float *Wa, *Wb, *ba, *bb, *Wr, *br; float* zo;
    switch (t) {
        case 0: h = hm; x = xm; n = NM; Wa = W2r + 0 * 4096; Wb = W2r + 4 * 4096;
                ba = b2 + 0 * 64; bb = b2 + 4 * 64; Wr = Wres + 1 * 8192; br = bres + 1 * 64; zo = om; break;
        case 1: h = hd; x = xd; n = ND; Wa = W2r + 1 * 4096; Wb = W2r + 2 * 4096;
                ba = b2 + 1 * 64; bb = b2 + 2 * 64; Wr = Wres + 2 * 8192; br = bres + 2 * 64; zo = od; break;
        default: h = hc; x = xc; n = NC; Wa = W2r + 3 * 4096; Wb = W2r + 5 * 4096;
                ba = b2 + 3 * 64; bb = b2 + 5 * 64; Wr = Wres + 0 * 8192; br = bres + 0 * 64; zo = oc; break;
    }
    __shared__ float hs[64 * 68];
    __shared__ float xs[64 * 132];
    int tid = threadIdx.x;
    int node0 = lb * 64;
    for (int idx = tid; idx < 64 * 16; idx += 256) {
        int nn = idx >> 4, f4 = idx & 15;
        int g = node0 + nn;
        float4 v = make_float4(0.f, 0.f, 0.f, 0.f);
        if (g < n) v = ((const float4*)h)[(size_t)g * 16 + f4];
        *((float4*)(hs + nn * 68 + f4 * 4)) = v;
    }
    for (int idx = tid; idx < 64 * 32; idx += 256) {
        int nn = idx >> 5, f4 = idx & 31;
        int g = node0 + nn;
        float4 v = make_float4(0.f, 0.f, 0.f, 0.f);
        if (g < n) v = ((const float4*)x)[(size_t)g * 32 + f4];
        *((float4*)(xs + nn * 132 + f4 * 4)) = v;
    }
    __syncthreads();
    int jq = tid & 15, ng = tid >> 4;
    float4 bva = ((const float4*)ba)[jq];
    float4 bvb = ((const float4*)bb)[jq];
    float4 bvr = ((const float4*)br)[jq];
    float acc[4][4];
#pragma unroll
    for (int i = 0; i < 4; ++i) {
        acc[i][0] = 0.5f * (bva.x + bvb.x) + bvr.x;
        acc[i][1] = 0.5f * (bva.y + bvb.y) + bvr.y;
        acc[i][2] = 0.5f * (bva.z + bvb.z) + bvr.z;
        acc[i][3] = 0.5f * (bva.w + bvb.w) + bvr.w;
    }
#pragma unroll 4
    for (int k = 0; k < 64; k += 4) {
        float4 wv[4];
#pragma unroll
        for (int kk = 0; kk < 4; ++kk) {
            float4 a = ((const float4*)(Wa + (k + kk) * 64))[jq];
            float4 b2_ = ((const float4*)(Wb + (k + kk) * 64))[jq];
            wv[kk] = make_float4(0.5f * (a.x + b2_.x), 0.5f * (a.y + b2_.y),
                                 0.5f * (a.z + b2_.z), 0.5f * (a.w + b2_.w));
        }
#pragma unroll
        for (int i = 0; i < 4; ++i) {
            float4 xv = *((const float4*)(hs + (ng * 4 + i) * 68 + k));
            fma_nq(acc[i], xv, wv[0], wv[1], wv[2], wv[3]);
        }
    }
#pragma unroll 4
    for (int k = 0; k < 128; k += 4) {
        float4 wv0 = ((const float4*)(Wr + (k + 0) * 64))[jq];
        float4 wv1 = ((const float4*)(Wr + (k + 1) * 64))[jq];
        float4 wv2 = ((const float4*)(Wr + (k + 2) * 64))[jq];
        float4 wv3 = ((const float4*)(Wr + (k + 3) * 64))[jq];
#pragma unroll
        for (int i = 0; i < 4; ++i) {
            float4 xv = *((const float4*)(xs + (ng * 4 + i) * 132 + k));
            fma_nq(acc[i], xv, wv0, wv1, wv2, wv3);
        }
    }
#pragma unroll
    for (int i = 0; i < 4; ++i) {
        int g = node0 + ng * 4 + i;
        if (g < n) {
            float4 o = make_float4(acc[i][0], acc[i][1], acc[i][2], acc[i][3]);
            ((float4*)(zo + (size_t)g * 64))[jq] = o;
        }
    }
}

// fused aggregate over all 3 types, in-place on io (io holds z already):
// io[wid] = post(0.5*(mean(y1[csr])+mean(y2[csr])) + io[wid])
// wave order: m (NM), d (ND), c (NC); 4 waves/block, grid 40000
template<bool RELU, bool NORM>
__global__ __launch_bounds__(256) void agg_all_k(
    const float* __restrict__ y, const int* __restrict__ off,
    const int* __restrict__ csr,
    float* __restrict__ ioc, float* __restrict__ iom, float* __restrict__ iod)
{
    int w = blockIdx.x * 4 + (threadIdx.x >> 6);
    int t, wid;
    if (w < NM) { t = 0; wid = w; }
    else if (w < NM + ND) { t = 1; wid = w - NM; }
    else { t = 2; wid = w - NM - ND; }
    const int *o1, *o2; const float *y1, *y2; float* io;
    switch (t) {
        case 0: o1 = off + SB0; o2 = off + SB4; y1 = y + (size_t)R0 * 64; y2 = y + (size_t)R4 * 64; io = iom; break;
        case 1: o1 = off + SB1; o2 = off + SB2; y1 = y + (size_t)R1 * 64; y2 = y + (size_t)R2 * 64; io = iod; break;
        default: o1 = off + SB3; o2 = off + SB5; y1 = y + (size_t)R3 * 64; y2 = y + (size_t)R5 * 64; io = ioc; break;
    }
    int lane = threadIdx.x & 63;
    int q = lane >> 4, ql = lane & 15;
    float4 acc = make_float4(0.f, 0.f, 0.f, 0.f);
    {
        int e0 = o1[wid], e1 = o1[wid + 1];
        float4 a = make_float4(0.f, 0.f, 0.f, 0.f);
        int e = e0 + q;
        for (; e + 4 < e1; e += 8) {
            int sA = csr[e], sB = csr[e + 4];
            float4 vA = ((const float4*)(y1 + ((size_t)sA << 6)))[ql];
            float4 vB = ((const float4*)(y1 + ((size_t)sB << 6)))[ql];
            a.x += vA.x + vB.x; a.y += vA.y + vB.y;
            a.z += vA.z + vB.z; a.w += vA.w + vB.w;
        }
        if (e < e1) {
            float4 v = ((const float4*)(y1 + ((size_t)csr[e] << 6)))[ql];
            a.x += v.x; a.y += v.y; a.z += v.z; a.w += v.w;
        }
        float inv = 1.f / fmaxf((float)(e1 - e0), 1.f);
        acc.x += a.x * inv; acc.y += a.y * inv; acc.z += a.z * inv; acc.w += a.w * inv;
    }
    {
        int e0 = o2[wid], e1 = o2[wid + 1];
        float4 a = make_float4(0.f, 0.f, 0.f, 0.f);
        int e = e0 + q;
        for (; e + 4 < e1; e += 8) {
            int sA = csr[e], sB = csr[e + 4];
            float4 vA = ((const float4*)(y2 + ((size_t)sA << 6)))[ql];
            float4 vB = ((const float4*)(y2 + ((size_t)sB << 6)))[ql];
            a.x += vA.x + vB.x; a.y += vA.y + vB.y;
            a.z += vA.z + vB.z; a.w += vA.w + vB.w;
        }
        if (e < e1) {
            float4 v = ((const float4*)(y2 + ((size_t)csr[e] << 6)))[ql];
            a.x += v.x; a.y += v.y; a.z += v.z; a.w += v.w;
        }
        float inv = 1.f / fmaxf((float)(e1 - e0), 1.f);
        acc.x += a.x * inv; acc.y += a.y * inv; acc.z += a.z * inv; acc.w += a.w * inv;
    }
    acc.x += __shfl_xor(acc.x, 16); acc.y += __shfl_xor(acc.y, 16);
    acc.z += __shfl_xor(acc.z, 16); acc.w += __shfl_xor(acc.w, 16);
    acc.x += __shfl_xor(acc.x, 32); acc.y += __shfl_xor(acc.y, 32);
    acc.z += __shfl_xor(acc.z, 32); acc.w += __shfl_xor(acc.w, 32);
    if (q == 0) {
        float4 zz = ((const float4*)(io + ((size_t)wid << 6)))[ql];
        float4 o = make_float4(0.5f * acc.x + zz.x, 0.5f * acc.y + zz.y,
                               0.5f * acc.z + zz.z, 0.5f * acc.w + zz.w);
        if (RELU) {
            o.x = fmaxf(o.x, 0.f); o.y = fmaxf(o.y, 0.f);
            o.z = fmaxf(o.z, 0.f); o.w = fmaxf(o.w, 0.f);
        }
        if (NORM) {
            float ss = o.x * o.x + o.y * o.y + o.z * o.z + o.w * o.w;
            ss += __shfl_xor(ss, 1); ss += __shfl_xor(ss, 2);
            ss += __shfl_xor(ss, 4); ss += __shfl_xor(ss, 8);
            float r = 1.f / fmaxf(sqrtf(ss), 1e-12f);
            o.x *= r; o.y *= r; o.z *= r; o.w *= r;
        }
        ((float4*)(io + ((size_t)wid << 6)))[ql] = o;
    }
}

extern "C" void kernel_launch(void* const* d_in, const int* in_sizes, int n_in,
                              void* d_out, int out_size, void* d_ws, size_t ws_size,
                              hipStream_t stream) {
    const float* x_c = (const float*)d_in[0];
    const float* x_m = (const float*)d_in[1];
    const float* x_d = (const float*)d_in[2];
    const int* src_cm = (const int*)d_in[3];
    const int* dst_cm = (const int*)d_in[4];
    const int* src_md = (const int*)d_in[5];
    const int* dst_md = (const int*)d_in[6];
    const int* src_cd = (const int*)d_in[7];
    const int* dst_cd = (const int*)d_in[8];
    const int* src_mc = (const int*)d_in[9];
    const int* dst_mc = (const int*)d_in[10];
    const int* src_dm = (const int*)d_in[11];
    const int* dst_dm = (const int*)d_in[12];
    const int* src_dc = (const int*)d_in[13];
    const int* dst_dc = (const int*)d_in[14];
    const float* W1l = (const float*)d_in[15];  // [6][128][64]
    const float* W1r = (const float*)d_in[16];
    const float* b1 = (const float*)d_in[17];   // [6][64]
    const float* W2l = (const float*)d_in[18];  // [6][64][64]
    const float* W2r = (const float*)d_in[19];
    const float* b2 = (const float*)d_in[20];
    const float* Wres = (const float*)d_in[21]; // [3][128][64]
    const float* bres = (const float*)d_in[22]; // [3][64]
    float* out = (float*)d_out;

    // workspace
    int* off = (int*)d_ws;                 // 320064
    int* csr = off + 320064;               // 4,800,000
    int* bhist = csr + 4800000;            // 2400
    int* bOff = bhist + 2400;              // 2404
    int* bCur = bOff + 2404;               // 2404
    float* h = (float*)(bCur + 2404);      // 160000*64 floats: [c|m|d]
    float* h_c = h;
    float* h_m = h_c + (size_t)NC * 64;
    float* h_d = h_m + (size_t)NM * 64;
    float* y = h + (size_t)160000 * 64;    // 320000*64 floats
    int* bArr = (int*)y;                   // 4.8M ints, aliased with y (dead after build)

    float* out_c = out;
    float* out_m = out + (size_t)NC * 64;
    float* out_d = out_m + (size_t)NM * 64;

    // ---- CSR build ----
    zero_k<<<(NB + 255) / 256, 256, 0, stream>>>(bhist, NB);
    bucket_hist_k<<<dim3(EBL, 6), 256, 0, stream>>>(dst_cm, dst_md, dst_cd, dst_mc, dst_dm, dst_dc, bhist);
    bucket_scan_k<<<1, 256, 0, stream>>>(bhist, bOff, bCur, off);
    partition_k<<<dim3(PBL, 6), 512, 0, stream>>>(src_cm, dst_cm, src_md, dst_md, src_cd, dst_cd,
                                                  src_mc, dst_mc, src_dm, dst_dm, src_dc, dst_dc,
                                                  bCur, bArr);
    bucket_build_k<<<NB, 256, 0, stream>>>(bArr, bOff, off, csr);

    // ---- layer 1 ----
    gemmy_all_k<128><<<5004, 256, 0, stream>>>(x_c, x_m, x_d, W1l, y);
    gemmz1_all_k<<<2502, 256, 0, stream>>>(x_c, x_m, x_d, W1r, b1, h_c, h_m, h_d);
    agg_all_k<true, false><<<40000, 256, 0, stream>>>(y, off, csr, h_c, h_m, h_d);

    // ---- layer 2 ----
    gemmy_all_k<64><<<5004, 256, 0, stream>>>(h_c, h_m, h_d, W2l, y);
    gemmz2_all_k<<<2502, 256, 0, stream>>>(h_c, h_m, h_d, x_c, x_m, x_d,
                                           W2r, b2, Wres, bres, out_c, out_m, out_d);
    agg_all_k<false, true><<<40000, 256, 0, stream>>>(y, off, csr, out_c, out_m, out_d);
}

// Round 6
// 893.667 us; speedup vs baseline: 3.5707x; 1.1714x over previous
//
#include <hip/hip_runtime.h>
#include <cstdint>
#include <cstddef>

#define EE        800000
#define NC        100000
#define NM        50000
#define ND        10000
#define NSLOTS    320000

// relation order: 0=c->m, 1=m->d, 2=c->d, 3=m->c, 4=d->m, 5=d->c
#define SB0 0
#define SB1 50000
#define SB2 60000
#define SB3 70000
#define SB4 170000
#define SB5 220000

// y_all row offsets per relation (src-transformed tables)
#define R0 0
#define R1 100000
#define R2 150000
#define R3 250000
#define R4 300000
#define R5 310000

// buckets: 400/relation; spb: {125,25,25,250,125,250}
#define NB 2400
#define EPB 4096
#define EBL 196
#define EPB2 8192
#define PBL 98
#define BCAP 3072

__global__ __launch_bounds__(256) void zero_k(int* p, int n) {
    int i = blockIdx.x * 256 + threadIdx.x;
    if (i < n) p[i] = 0;
}

__device__ __forceinline__ void bucket_split(int rel, int d, int& lb, int& dl) {
    switch (rel) {
        case 0: case 4: lb = d / 125; dl = d - lb * 125; break;
        case 1: case 2: lb = d / 25;  dl = d - lb * 25;  break;
        default:        lb = d / 250; dl = d - lb * 250; break;
    }
}

__global__ __launch_bounds__(256) void bucket_hist_k(
    const int* __restrict__ d0, const int* __restrict__ d1, const int* __restrict__ d2,
    const int* __restrict__ d3, const int* __restrict__ d4, const int* __restrict__ d5,
    int* __restrict__ bhist)
{
    __shared__ int hl[400];
    int rel = blockIdx.y;
    const int* dst;
    switch (rel) {
        case 0: dst = d0; break; case 1: dst = d1; break; case 2: dst = d2; break;
        case 3: dst = d3; break; case 4: dst = d4; break; default: dst = d5; break;
    }
    int tid = threadIdx.x;
    for (int i = tid; i < 400; i += 256) hl[i] = 0;
    __syncthreads();
    int e0 = blockIdx.x * EPB;
#pragma unroll
    for (int t = 0; t < EPB / 256; ++t) {
        int e = e0 + t * 256 + tid;
        if (e < EE) {
            int lb, dl;
            bucket_split(rel, dst[e], lb, dl);
            atomicAdd(&hl[lb], 1);
        }
    }
    __syncthreads();
    for (int i = tid; i < 400; i += 256) {
        int v = hl[i];
        if (v) atomicAdd(&bhist[rel * 400 + i], v);
    }
}

__global__ __launch_bounds__(256) void bucket_scan_k(const int* __restrict__ bhist,
    int* __restrict__ bOff, int* __restrict__ bCur, int* __restrict__ off)
{
    __shared__ int lds[256];
    int tid = threadIdx.x;
    int v[10];
    int tot = 0;
#pragma unroll
    for (int t = 0; t < 10; ++t) {
        int idx = tid * 10 + t;
        int x = (idx < NB) ? bhist[idx] : 0;
        v[t] = tot;
        tot += x;
    }
    lds[tid] = tot;
    __syncthreads();
    for (int o = 1; o < 256; o <<= 1) {
        int x = 0;
        if (tid >= o) x = lds[tid - o];
        __syncthreads();
        lds[tid] += x;
        __syncthreads();
    }
    int excl = lds[tid] - tot;
#pragma unroll
    for (int t = 0; t < 10; ++t) {
        int idx = tid * 10 + t;
        if (idx < NB) {
            int val = excl + v[t];
            bOff[idx] = val;
            bCur[idx] = val;
        }
    }
    if (tid == 255) {
        bOff[NB] = lds[255];
        off[NSLOTS] = lds[255];
    }
}

// block-private chunk reservation; packed payload = (dstLocal<<17)|src
__global__ __launch_bounds__(512) void partition_k(
    const int* __restrict__ s0, const int* __restrict__ d0,
    const int* __restrict__ s1, const int* __restrict__ d1,
    const int* __restrict__ s2, const int* __restrict__ d2,
    const int* __restrict__ s3, const int* __restrict__ d3,
    const int* __restrict__ s4, const int* __restrict__ d4,
    const int* __restrict__ s5, const int* __restrict__ d5,
    int* __restrict__ bCur, int* __restrict__ bArr)
{
    __shared__ int hist[400];
    __shared__ int curs[400];
    __shared__ unsigned short lbs[EPB2];
    __shared__ unsigned char dls[EPB2];
    int rel = blockIdx.y;
    const int* src; const int* dst;
    switch (rel) {
        case 0: src = s0; dst = d0; break;
        case 1: src = s1; dst = d1; break;
        case 2: src = s2; dst = d2; break;
        case 3: src = s3; dst = d3; break;
        case 4: src = s4; dst = d4; break;
        default: src = s5; dst = d5; break;
    }
    int tid = threadIdx.x;
    for (int i = tid; i < 400; i += 512) hist[i] = 0;
    __syncthreads();
    int e0 = blockIdx.x * EPB2;
    int e1 = e0 + EPB2; if (e1 > EE) e1 = EE;
    int m = e1 - e0;
    for (int i = tid; i < m; i += 512) {
        int lb, dl;
        bucket_split(rel, dst[e0 + i], lb, dl);
        lbs[i] = (unsigned short)lb;
        dls[i] = (unsigned char)dl;
        atomicAdd(&hist[lb], 1);
    }
    __syncthreads();
    for (int i = tid; i < 400; i += 512) {
        int c = hist[i];
        curs[i] = c ? atomicAdd(&bCur[rel * 400 + i], c) : 0;
    }
    __syncthreads();
    for (int i = tid; i < m; i += 512) {
        int p = atomicAdd(&curs[lbs[i]], 1);
        bArr[p] = ((int)dls[i] << 17) | src[e0 + i];
    }
}

__global__ __launch_bounds__(256) void bucket_build_k(
    const int* __restrict__ bArr, const int* __restrict__ bOff,
    int* __restrict__ off, int* __restrict__ csr)
{
    __shared__ int cnt[256];
    __shared__ int sc[256];
    __shared__ int cur[256];
    __shared__ int stage[BCAP];
    int b = blockIdx.x;
    int tid = threadIdx.x;
    int r = b / 400;
    int lb = b - r * 400;
    int spb, sbase;
    switch (r) {
        case 0: spb = 125; sbase = SB0; break;
        case 1: spb = 25;  sbase = SB1; break;
        case 2: spb = 25;  sbase = SB2; break;
        case 3: spb = 250; sbase = SB3; break;
        case 4: spb = 125; sbase = SB4; break;
        default: spb = 250; sbase = SB5; break;
    }
    int slot0 = lb * spb;
    int e0 = bOff[b], e1 = bOff[b + 1];
    int m = e1 - e0;
    int ms = m < BCAP ? m : BCAP;

    cnt[tid] = 0;
    __syncthreads();
    for (int i = tid; i < ms; i += 256) {
        int p = bArr[e0 + i];
        stage[i] = p;
        atomicAdd(&cnt[p >> 17], 1);
    }
    for (int i = BCAP + tid; i < m; i += 256) {
        int p = bArr[e0 + i];
        atomicAdd(&cnt[p >> 17], 1);
    }
    __syncthreads();
    int x = cnt[tid];
    sc[tid] = x;
    __syncthreads();
    for (int o = 1; o < 256; o <<= 1) {
        int y = 0;
        if (tid >= o) y = sc[tid - o];
        __syncthreads();
        sc[tid] += y;
        __syncthreads();
    }
    int excl = sc[tid] - x;
    cur[tid] = excl;
    if (tid < spb) off[sbase + slot0 + tid] = e0 + excl;
    __syncthreads();
    for (int i = tid; i < ms; i += 256) {
        int p = stage[i];
        int pos = atomicAdd(&cur[p >> 17], 1);
        csr[e0 + pos] = p & 0x1FFFF;
    }
    for (int i = BCAP + tid; i < m; i += 256) {
        int p = bArr[e0 + i];
        int pos = atomicAdd(&cur[p >> 17], 1);
        csr[e0 + pos] = p & 0x1FFFF;
    }
}

__device__ __forceinline__ void fma_nq(float* acc, float4 xv, float4 w0, float4 w1, float4 w2, float4 w3) {
    acc[0] += xv.x * w0.x + xv.y * w1.x + xv.z * w2.x + xv.w * w3.x;
    acc[1] += xv.x * w0.y + xv.y * w1.y + xv.z * w2.y + xv.w * w3.y;
    acc[2] += xv.x * w0.z + xv.y * w1.z + xv.z * w2.z + xv.w * w3.z;
    acc[3] += xv.x * w0.w + xv.y * w1.w + xv.z * w2.w + xv.w * w3.w;
}

__device__ __forceinline__ unsigned f2bf(float f) {   // RNE
    unsigned b = __float_as_uint(f);
    return (b + 0x7FFFu + ((b >> 16) & 1u)) >> 16;
}
__device__ __forceinline__ unsigned pack2(float lo, float hi) {
    return (f2bf(hi) << 16) | f2bf(lo);
}

// all-6-relation y GEMM (bf16 output): y[rowOff+g] = feat_src(r)[g] @ Wl[r]
template<int K>
__global__ __launch_bounds__(256) void gemmy_all_k(
    const float* __restrict__ fc, const float* __restrict__ fm, const float* __restrict__ fd,
    const float* __restrict__ Wl, unsigned short* __restrict__ y)
{
    int b = blockIdx.x;
    int r, lb;
    if (b < 1563)      { r = 0; lb = b; }
    else if (b < 2345) { r = 1; lb = b - 1563; }
    else if (b < 3908) { r = 2; lb = b - 2345; }
    else if (b < 4690) { r = 3; lb = b - 3908; }
    else if (b < 4847) { r = 4; lb = b - 4690; }
    else               { r = 5; lb = b - 4847; }
    const float* x; int n; int rowOff;
    switch (r) {
        case 0: x = fc; n = NC; rowOff = R0; break;
        case 1: x = fm; n = NM; rowOff = R1; break;
        case 2: x = fc; n = NC; rowOff = R2; break;
        case 3: x = fm; n = NM; rowOff = R3; break;
        case 4: x = fd; n = ND; rowOff = R4; break;
        default: x = fd; n = ND; rowOff = R5; break;
    }
    const float* W = Wl + (size_t)r * K * 64;
    unsigned short* yo = y + (size_t)rowOff * 64;

    constexpr int KP = K + 4;
    __shared__ float xs[64 * KP];
    int tid = threadIdx.x;
    int node0 = lb * 64;
    constexpr int Q = K / 4;
    for (int idx = tid; idx < 64 * Q; idx += 256) {
        int nn = idx / Q, f4 = idx % Q;
        int g = node0 + nn;
        float4 v = make_float4(0.f, 0.f, 0.f, 0.f);
        if (g < n) v = ((const float4*)x)[(size_t)g * Q + f4];
        *((float4*)(xs + nn * KP + f4 * 4)) = v;
    }
    __syncthreads();
    int jq = tid & 15, ng = tid >> 4;
    float acc[4][4] = {};
#pragma unroll 4
    for (int k = 0; k < K; k += 4) {
        float4 wv0 = ((const float4*)(W + (k + 0) * 64))[jq];
        float4 wv1 = ((const float4*)(W + (k + 1) * 64))[jq];
        float4 wv2 = ((const float4*)(W + (k + 2) * 64))[jq];
        float4 wv3 = ((const float4*)(W + (k + 3) * 64))[jq];
#pragma unroll
        for (int i = 0; i < 4; ++i) {
            float4 xv = *((const float4*)(xs + (ng * 4 + i) * KP + k));
            fma_nq(acc[i], xv, wv0, wv1, wv2, wv3);
        }
    }
#pragma unroll
    for (int i = 0; i < 4; ++i) {
        int g = node0 + ng * 4 + i;
        if (g < n) {
            uint2 o = make_uint2(pack2(acc[i][0], acc[i][1]), pack2(acc[i][2], acc[i][3]));
            ((uint2*)(yo + (size_t)g * 64))[jq] = o;
        }
    }
}

// L1 z into h: z = 0.5*(x@(Wa+Wb)+ba+bb); K=128. type order m,d,c; prefix {782,939,2502}
__global__ __launch_bounds__(256) void gemmz1_all_k(
    const float* __restrict__ fc, const float* __restrict__ fm, const float* __restrict__ fd,
    const float* __restrict__ W1r, const float* __restrict__ b1,
    float* __restrict__ hc, float* __restrict__ hm, float* __restrict__ hd)
{
    int b = blockIdx.x;
    int t, lb;
    if (b < 782)      { t = 0; lb = b; }
    else if (b < 939) { t = 1; lb = b - 782; }
    else              { t = 2; lb = b - 939; }
    const float* x; int n; const float *Wa, *Wb, *ba, *bb; float* zo;
    switch (t) {
        case 0: x = fm; n = NM; Wa = W1r + 0 * 8192; Wb = W1r + 4 * 8192; ba = b1 + 0 * 64; bb = b1 + 4 * 64; zo = hm; break;
        case 1: x = fd; n = ND; Wa = W1r + 1 * 8192; Wb = W1r + 2 * 8192; ba = b1 + 1 * 64; bb = b1 + 2 * 64; zo = hd; break;
        default: x = fc; n = NC; Wa = W1r + 3 * 8192; Wb = W1r + 5 * 8192; ba = b1 + 3 * 64; bb = b1 + 5 * 64; zo = hc; break;
    }
    __shared__ float xs[64 * 132];
    int tid = threadIdx.x;
    int node0 = lb * 64;
    for (int idx = tid; idx < 64 * 32; idx += 256) {
        int nn = idx >> 5, f4 = idx & 31;
        int g = node0 + nn;
        float4 v = make_float4(0.f, 0.f, 0.f, 0.f);
        if (g < n) v = ((const float4*)x)[(size_t)g * 32 + f4];
        *((float4*)(xs + nn * 132 + f4 * 4)) = v;
    }
    __syncthreads();
    int jq = tid & 15, ng = tid >> 4;
    float4 bva = ((const float4*)ba)[jq];
    float4 bvb = ((const float4*)bb)[jq];
    float acc[4][4];
#pragma unroll
    for (int i = 0; i < 4; ++i) {
        acc[i][0] = 0.5f * (bva.x + bvb.x);
        acc[i][1] = 0.5f * (bva.y + bvb.y);
        acc[i][2] = 0.5f * (bva.z + bvb.z);
        acc[i][3] = 0.5f * (bva.w + bvb.w);
    }
#pragma unroll 4
    for (int k = 0; k < 128; k += 4) {
        float4 wv[4];
#pragma unroll
        for (int kk = 0; kk < 4; ++kk) {
            float4 a = ((const float4*)(Wa + (k + kk) * 64))[jq];
            float4 b2_ = ((const float4*)(Wb + (k + kk) * 64))[jq];
            wv[kk] = make_float4(0.5f * (a.x + b2_.x), 0.5f * (a.y + b2_.y),
                                 0.5f * (a.z + b2_.z), 0.5f * (a.w + b2_.w));
        }
#pragma unroll
        for (int i = 0; i < 4; ++i) {
            float4 xv = *((const float4*)(xs + (ng * 4 + i) * 132 + k));
            fma_nq(acc[i], xv, wv[0], wv[1], wv[2], wv[3]);
        }
    }
#pragma unroll
    for (int i = 0; i < 4; ++i) {
        int g = node0 + ng * 4 + i;
        if (g < n) {
            float4 o = make_float4(acc[i][0], acc[i][1], acc[i][2], acc[i][3]);
            ((float4*)(zo + (size_t)g * 64))[jq] = o;
        }
    }
}

// L2 z into out: z = 0.5*(h@(Wa+Wb)+ba+bb) + x@Wres + bres
__global__ __launch_bounds__(256) void gemmz2_all_k(
    const float* __restrict__ hc, const float* __restrict__ hm, const float* __restrict__ hd,
    const float* __restrict__ xc, const float* __restrict__ xm, const float* __restrict__ xd,
    const float* __restrict__ W2r, const float* __restrict__ b2,
    const float* __restrict__ Wres, const float* __restrict__ bres,
    float* __restrict__ oc, float* __restrict__ om, float* __restrict__ od)
{
    int b = blockIdx.x;
    int t, lb;
    if (b < 782)      { t = 0; lb = b; }
    else if (b < 939) { t = 1; lb = b - 782; }
    else              { t = 2; lb = b - 939; }
    const float *h, *x; int n; const float *Wa, *Wb, *ba, *bb, *Wr, *br; float* zo;
    switch (t) {
        case 0: h = hm; x = xm; n = NM; Wa = W2r + 0 * 4096; Wb = W2r + 4 * 4096;
                ba = b2 + 0 * 64; bb = b2 + 4 * 64; Wr = Wres + 1 * 8192; br = bres + 1 * 64; zo = om; break;
        case 1: h = hd; x = xd; n = ND; Wa = W2r + 1 * 4096; Wb = W2r + 2 * 4096;
                ba = b2 + 1 * 64; bb = b2 + 2 * 64; Wr = Wres + 2 * 8192; br = bres + 2 * 64; zo = od; break;
        default: h = hc; x = xc; n = NC; Wa = W2r + 3 * 4096; Wb = W2r + 5 * 4096;
                ba = b2 + 3 * 64; bb = b2 + 5 * 64; Wr = Wres + 0 * 8192; br = bres + 0 * 64; zo = oc; break;
    }
    __shared__ float hs[64 * 68];
    __shared__ float xs[64 * 132];
    int tid = threadIdx.x;
    int node0 = lb * 64;
    for (int idx = tid; idx < 64 * 16; idx += 256) {
        int nn = idx >> 4, f4 = idx & 15;
        int g = node0 + nn;
        float4 v = make_float4(0.f, 0.f, 0.f, 0.f);
        if (g < n) v = ((const float4*)h)[(size_t)g * 16 + f4];
        *((float4*)(hs + nn * 68 + f4 * 4)) = v;
    }
    for (int idx = tid; idx < 64 * 32; idx += 256) {
        int nn = idx >> 5, f4 = idx & 31;
        int g = node0 + nn;
        float4 v = make_float4(0.f, 0.f, 0.f, 0.f);
        if (g < n) v = ((const float4*)x)[(size_t)g * 32 + f4];
        *((float4*)(xs + nn * 132 + f4 * 4)) = v;
    }
    __syncthreads();
    int jq = tid & 15, ng = tid >> 4;
    float4 bva = ((const float4*)ba)[jq];
    float4 bvb = ((const float4*)bb)[jq];
    float4 bvr = ((const float4*)br)[jq];
    float acc[4][4];
#pragma unroll
    for (int i = 0; i < 4; ++i) {
        acc[i][0] = 0.5f * (bva.x + bvb.x) + bvr.x;
        acc[i][1] = 0.5f * (bva.y + bvb.y) + bvr.y;
        acc[i][2] = 0.5f * (bva.z + bvb.z) + bvr.z;
        acc[i][3] = 0.5f * (bva.w + bvb.w) + bvr.w;
    }
#pragma unroll 4
    for (int k = 0; k < 64; k += 4) {
        float4 wv[4];
#pragma unroll
        for (int kk = 0; kk < 4; ++kk) {
            float4 a = ((const float4*)(Wa + (k + kk) * 64))[jq];
            float4 b2_ = ((const float4*)(Wb + (k + kk) * 64))[jq];
            wv[kk] = make_float4(0.5f * (a.x + b2_.x), 0.5f * (a.y + b2_.y),
                                 0.5f * (a.z + b2_.z), 0.5f * (a.w + b2_.w));
        }
#pragma unroll
        for (int i = 0; i < 4; ++i) {
            float4 xv = *((const float4*)(hs + (ng * 4 + i) * 68 + k));
            fma_nq(acc[i], xv, wv[0], wv[1], wv[2], wv[3]);
        }
    }
#pragma unroll 4
    for (int k = 0; k < 128; k += 4) {
        float4 wv0 = ((const float4*)(Wr + (k + 0) * 64))[jq];
        float4 wv1 = ((const float4*)(Wr + (k + 1) * 64))[jq];
        float4 wv2 = ((const float4*)(Wr + (k + 2) * 64))[jq];
        float4 wv3 = ((const float4*)(Wr + (k + 3) * 64))[jq];
#pragma unroll
        for (int i = 0; i < 4; ++i) {
            float4 xv = *((const float4*)(xs + (ng * 4 + i) * 132 + k));
            fma_nq(acc[i], xv, wv0, wv1, wv2, wv3);
        }
    }
#pragma unroll
    for (int i = 0; i < 4; ++i) {
        int g = node0 + ng * 4 + i;
        if (g < n) {
            float4 o = make_float4(acc[i][0], acc[i][1], acc[i][2], acc[i][3]);
            ((float4*)(zo + (size_t)g * 64))[jq] = o;
        }
    }
}

__device__ __forceinline__ void acc_bf8(float* a, uint4 v) {
    a[0] += __uint_as_float(v.x << 16); a[1] += __uint_as_float(v.x & 0xFFFF0000u);
    a[2] += __uint_as_float(v.y << 16); a[3] += __uint_as_float(v.y & 0xFFFF0000u);
    a[4] += __uint_as_float(v.z << 16); a[5] += __uint_as_float(v.z & 0xFFFF0000u);
    a[6] += __uint_as_float(v.w << 16); a[7] += __uint_as_float(v.w & 0xFFFF0000u);
}

// fused aggregate (bf16 y): io[wid] = post(0.5*(mean(y1[csr])+mean(y2[csr])) + io[wid])
// wave = 8 groups x 8 lanes; group handles every-8th edge; lane loads 16B (8 bf16)
template<bool RELU, bool NORM>
__global__ __launch_bounds__(256) void agg_all_k(
    const unsigned short* __restrict__ y, const int* __restrict__ off,
    const int* __restrict__ csr,
    float* __restrict__ ioc, float* __restrict__ iom, float* __restrict__ iod)
{
    int w = blockIdx.x * 4 + (threadIdx.x >> 6);
    int t, wid;
    if (w < NM) { t = 0; wid = w; }
    else if (w < NM + ND) { t = 1; wid = w - NM; }
    else { t = 2; wid = w - NM - ND; }
    const int *o1, *o2; const unsigned short *y1, *y2; float* io;
    switch (t) {
        case 0: o1 = off + SB0; o2 = off + SB4; y1 = y + (size_t)R0 * 64; y2 = y + (size_t)R4 * 64; io = iom; break;
        case 1: o1 = off + SB1; o2 = off + SB2; y1 = y + (size_t)R1 * 64; y2 = y + (size_t)R2 * 64; io = iod; break;
        default: o1 = off + SB3; o2 = off + SB5; y1 = y + (size_t)R3 * 64; y2 = y + (size_t)R5 * 64; io = ioc; break;
    }
    int lane = threadIdx.x & 63;
    int g = lane >> 3, ql = lane & 7;   // group, quarter-lane
    float acc[8];
#pragma unroll
    for (int j = 0; j < 8; ++j) acc[j] = 0.f;
    {
        int e0 = o1[wid], e1 = o1[wid + 1];
        float a[8];
#pragma unroll
        for (int j = 0; j < 8; ++j) a[j] = 0.f;
        int e = e0 + g;
        for (; e + 8 < e1; e += 16) {
            uint4 vA = ((const uint4*)(y1 + ((size_t)csr[e] << 6)))[ql];
            uint4 vB = ((const uint4*)(y1 + ((size_t)csr[e + 8] << 6)))[ql];
            acc_bf8(a, vA);
            acc_bf8(a, vB);
        }
        if (e < e1) {
            uint4 v = ((const uint4*)(y1 + ((size_t)csr[e] << 6)))[ql];
            acc_bf8(a, v);
        }
        float inv = 1.f / fmaxf((float)(e1 - e0), 1.f);
#pragma unroll
        for (int j = 0; j < 8; ++j) acc[j] += a[j] * inv;
    }
    {
        int e0 = o2[wid], e1 = o2[wid + 1];
        float a[8];
#pragma unroll
        for (int j = 0; j < 8; ++j) a[j] = 0.f;
        int e = e0 + g;
        for (; e + 8 < e1; e += 16) {
            uint4 vA = ((const uint4*)(y2 + ((size_t)csr[e] << 6)))[ql];
            uint4 vB = ((const uint4*)(y2 + ((size_t)csr[e + 8] << 6)))[ql];
            acc_bf8(a, vA);
            acc_bf8(a, vB);
        }
        if (e < e1) {
            uint4 v = ((const uint4*)(y2 + ((size_t)csr[e] << 6)))[ql];
            acc_bf8(a, v);
        }
        float inv = 1.f / fmaxf((float)(e1 - e0), 1.f);
#pragma unroll
        for (int j = 0; j < 8; ++j) acc[j] += a[j] * inv;
    }
    // reduce across the 8 groups
#pragma unroll
    for (int j = 0; j < 8; ++j) {
        acc[j] += __shfl_xor(acc[j], 8);
        acc[j] += __shfl_xor(acc[j], 16);
        acc[j] += __shfl_xor(acc[j], 32);
    }
    if (g == 0) {
        float* iorow = io + ((size_t)wid << 6) + ql * 8;
        float4 z1 = *((const float4*)iorow);
        float4 z2 = *((const float4*)(iorow + 4));
        float o[8];
        o[0] = 0.5f * acc[0] + z1.x; o[1] = 0.5f * acc[1] + z1.y;
        o[2] = 0.5f * acc[2] + z1.z; o[3] = 0.5f * acc[3] + z1.w;
        o[4] = 0.5f * acc[4] + z2.x; o[5] = 0.5f * acc[5] + z2.y;
        o[6] = 0.5f * acc[6] + z2.z; o[7] = 0.5f * acc[7] + z2.w;
        if (RELU) {
#pragma unroll
            for (int j = 0; j < 8; ++j) o[j] = fmaxf(o[j], 0.f);
        }
        if (NORM) {
            float ss = 0.f;
#pragma unroll
            for (int j = 0; j < 8; ++j) ss += o[j] * o[j];
            ss += __shfl_xor(ss, 1); ss += __shfl_xor(ss, 2); ss += __shfl_xor(ss, 4);
            float r = 1.f / fmaxf(sqrtf(ss), 1e-12f);
#pragma unroll
            for (int j = 0; j < 8; ++j) o[j] *= r;
        }
        *((float4*)iorow) = make_float4(o[0], o[1], o[2], o[3]);
        *((float4*)(iorow + 4)) = make_float4(o[4], o[5], o[6], o[7]);
    }
}

extern "C" void kernel_launch(void* const* d_in, const int* in_sizes, int n_in,
                              void* d_out, int out_size, void* d_ws, size_t ws_size,
                              hipStream_t stream) {
    const float* x_c = (const float*)d_in[0];
    const float* x_m = (const float*)d_in[1];
    const float* x_d = (const float*)d_in[2];
    const int* src_cm = (const int*)d_in[3];
    const int* dst_cm = (const int*)d_in[4];
    const int* src_md = (const int*)d_in[5];
    const int* dst_md = (const int*)d_in[6];
    const int* src_cd = (const int*)d_in[7];
    const int* dst_cd = (const int*)d_in[8];
    const int* src_mc = (const int*)d_in[9];
    const int* dst_mc = (const int*)d_in[10];
    const int* src_dm = (const int*)d_in[11];
    const int* dst_dm = (const int*)d_in[12];
    const int* src_dc = (const int*)d_in[13];
    const int* dst_dc = (const int*)d_in[14];
    const float* W1l = (const float*)d_in[15];  // [6][128][64]
    const float* W1r = (const float*)d_in[16];
    const float* b1 = (const float*)d_in[17];   // [6][64]
    const float* W2l = (const float*)d_in[18];  // [6][64][64]
    const float* W2r = (const float*)d_in[19];
    const float* b2 = (const float*)d_in[20];
    const float* Wres = (const float*)d_in[21]; // [3][128][64]
    const float* bres = (const float*)d_in[22]; // [3][64]
    float* out = (float*)d_out;

    // workspace
    int* off = (int*)d_ws;                 // 320064
    int* csr = off + 320064;               // 4,800,000
    int* bhist = csr + 4800000;            // 2400
    int* bOff = bhist + 2400;              // 2404
    int* bCur = bOff + 2404;               // 2404
    float* h = (float*)(bCur + 2404);      // 160000*64 floats: [c|m|d]
    float* h_c = h;
    float* h_m = h_c + (size_t)NC * 64;
    float* h_d = h_m + (size_t)NM * 64;
    unsigned short* y = (unsigned short*)(h + (size_t)160000 * 64); // 320000*64 bf16
    int* bArr = (int*)y;                   // 4.8M ints (19.2MB < 41MB), dead after build

    float* out_c = out;
    float* out_m = out + (size_t)NC * 64;
    float* out_d = out_m + (size_t)NM * 64;

    // ---- CSR build ----
    zero_k<<<(NB + 255) / 256, 256, 0, stream>>>(bhist, NB);
    bucket_hist_k<<<dim3(EBL, 6), 256, 0, stream>>>(dst_cm, dst_md, dst_cd, dst_mc, dst_dm, dst_dc, bhist);
    bucket_scan_k<<<1, 256, 0, stream>>>(bhist, bOff, bCur, off);
    partition_k<<<dim3(PBL, 6), 512, 0, stream>>>(src_cm, dst_cm, src_md, dst_md, src_cd, dst_cd,
                                                  src_mc, dst_mc, src_dm, dst_dm, src_dc, dst_dc,
                                                  bCur, bArr);
    bucket_build_k<<<NB, 256, 0, stream>>>(bArr, bOff, off, csr);

    // ---- layer 1 ----
    gemmy_all_k<128><<<5004, 256, 0, stream>>>(x_c, x_m, x_d, W1l, y);
    gemmz1_all_k<<<2502, 256, 0, stream>>>(x_c, x_m, x_d, W1r, b1, h_c, h_m, h_d);
    agg_all_k<true, false><<<40000, 256, 0, stream>>>(y, off, csr, h_c, h_m, h_d);

    // ---- layer 2 ----
    gemmy_all_k<64><<<5004, 256, 0, stream>>>(h_c, h_m, h_d, W2l, y);
    gemmz2_all_k<<<2502, 256, 0, stream>>>(h_c, h_m, h_d, x_c, x_m, x_d,
                                           W2r, b2, Wres, bres, out_c, out_m, out_d);
    agg_all_k<false, true><<<40000, 256, 0, stream>>>(y, off, csr, out_c, out_m, out_d);
}